// Round 10
// baseline (172.832 us; speedup 1.0000x reference)
//
#include <hip/hip_runtime.h>

#define N_INST 4096
#define D_FEAT 512
#define NHEAD 8
#define NPAIR 131072

typedef __attribute__((ext_vector_type(8))) short short8;
typedef __attribute__((ext_vector_type(4))) float f32x4;
typedef __attribute__((ext_vector_type(4))) unsigned short u16x4;

__device__ inline unsigned short f2bf(float f) {
  union { float f; unsigned u; } v; v.f = f;
  unsigned r = v.u + 0x7fffu + ((v.u >> 16) & 1u);
  return (unsigned short)(r >> 16);
}
__device__ inline float bf2f(unsigned short b) {
  union { unsigned u; float f; } v; v.u = ((unsigned)b) << 16; return v.f;
}
__device__ inline void gload16(const void* g, void* l) {
  __builtin_amdgcn_global_load_lds((const __attribute__((address_space(1))) unsigned int*)g,
                                   (__attribute__((address_space(3))) unsigned int*)l, 16, 0, 0);
}

// ---------------- both weight casts in one launch (y=0 -> w_q, y=1 -> w_k) ----------------
__global__ __launch_bounds__(256) void k_castw(const float* __restrict__ wq,
                                               const float* __restrict__ wk,
                                               unsigned short* __restrict__ dst) {
  const float* src = blockIdx.y ? wk : wq;
  unsigned short* d = dst + (size_t)blockIdx.y * D_FEAT * D_FEAT;
  int i = (blockIdx.x * 256 + threadIdx.x) * 4;
  float4 v = *(const float4*)&src[i];
  ushort4 o;
  o.x = f2bf(v.x); o.y = f2bf(v.y); o.z = f2bf(v.z); o.w = f2bf(v.w);
  *(ushort4*)&d[i] = o;
}

// ---------------- x (4096x512 f32) -> xb bf16 AND xT bf16 (512x4096), one read ----------------
__global__ __launch_bounds__(256) void k_xprep(const float* __restrict__ x,
                                               unsigned short* __restrict__ xb,
                                               unsigned short* __restrict__ xT) {
  __shared__ float t[32][33];
  int bx = blockIdx.x, by = blockIdx.y;
  int tx = threadIdx.x & 31, ty = threadIdx.x >> 5;
  #pragma unroll
  for (int r = 0; r < 4; ++r) {
    int row = by * 32 + ty + r * 8;
    float v = x[(size_t)row * D_FEAT + bx * 32 + tx];
    t[ty + r * 8][tx] = v;
    xb[(size_t)row * D_FEAT + bx * 32 + tx] = f2bf(v);
  }
  __syncthreads();
  #pragma unroll
  for (int r = 0; r < 4; ++r)
    xT[(size_t)(bx * 32 + ty + r * 8) * N_INST + by * 32 + tx] = f2bf(t[tx][ty + r * 8]);
}

// ---------------- block-per-row: 0/1 bf16 mask (diag=1) + off-diag count, NT streaming ----------------
__global__ __launch_bounds__(256) void k_mask_acnt(const float* __restrict__ agg,
                                                   unsigned short* __restrict__ maskb,
                                                   int* __restrict__ acnt) {
  int i = blockIdx.x;
  const f32x4* row = (const f32x4*)(agg + (size_t)i * N_INST);
  u16x4* mrow = (u16x4*)(maskb + (size_t)i * N_INST);
  int tid = threadIdx.x;
  f32x4 v[4];
  #pragma unroll
  for (int u = 0; u < 4; ++u)
    v[u] = __builtin_nontemporal_load(&row[u * 256 + tid]);
  int cnt = 0;
  #pragma unroll
  for (int u = 0; u < 4; ++u) {
    int t = u * 256 + tid;
    u16x4 m;
    m[0] = (v[u][0] != 0.f) ? 0x3F80 : 0;
    m[1] = (v[u][1] != 0.f) ? 0x3F80 : 0;
    m[2] = (v[u][2] != 0.f) ? 0x3F80 : 0;
    m[3] = (v[u][3] != 0.f) ? 0x3F80 : 0;
    cnt += (v[u][0] != 0.f) + (v[u][1] != 0.f) + (v[u][2] != 0.f) + (v[u][3] != 0.f);
    int j = t * 4;
    if (i >= j && i < j + 4) {
      int d = i - j;
      m[d] = 0x3F80;                    // diagonal always present
      cnt -= (v[u][d] != 0.f);          // diag not counted as generic
    }
    __builtin_nontemporal_store(m, &mrow[t]);
  }
  #pragma unroll
  for (int msk = 1; msk < 64; msk <<= 1) cnt += __shfl_xor(cnt, msk);
  __shared__ int wsum[4];
  if ((threadIdx.x & 63) == 0) wsum[threadIdx.x >> 6] = cnt;
  __syncthreads();
  if (threadIdx.x == 0) acnt[i] = wsum[0] + wsum[1] + wsum[2] + wsum[3];
}

// ---------------- NT bf16 MFMA GEMM, BM=128, BN templated (64 or 128), BK=64 ----------------
// gload_lds staging + LDS dbuf + granule swizzle + XCD-chunked tile swizzle.
// CBF16 path writes bf16 at z-offset (split-K bf16 partials: |p|<~100, err ~2e-4 on out).
template<int BIAS, int CBF16, int BN>
__global__ __launch_bounds__(256, 2) void k_gemm(const unsigned short* __restrict__ A,
                                                 const unsigned short* __restrict__ B,
                                                 const float* __restrict__ bias0,
                                                 const float* __restrict__ bias1,
                                                 void* __restrict__ Cv,
                                                 int M, int N, int K, int klen) {
  constexpr int NI = BN / 32;
  constexpr int BCH = BN / 32;
  __shared__ __align__(16) unsigned short lA[2][128 * 64];
  __shared__ __align__(16) unsigned short lB[2][BN * 64];
  int tid = threadIdx.x, wave = tid >> 6, lane = tid & 63;
  int wm = wave & 1, wn = wave >> 1;
  int gx = gridDim.x;
  int nxy = gx * gridDim.y;
  int lin = blockIdx.x + gx * blockIdx.y;
  int nch = nxy >> 3;
  int nl = (lin & 7) * nch + (lin >> 3);
  int bx = nl % gx, by = nl / gx;
  int bm = by * 128, bn = bx * BN;
  int kbase = blockIdx.z * klen;
  int srow = lane >> 3;
  int sg = (lane & 7) ^ srow;
  const unsigned short* ag[4];
  const unsigned short* bg[BCH];
  #pragma unroll
  for (int p = 0; p < 4; ++p) {
    int row = (wave * 4 + p) * 8 + srow;
    ag[p] = A + (size_t)(bm + row) * K + kbase + sg * 8;
  }
  #pragma unroll
  for (int p = 0; p < BCH; ++p) {
    int row = (wave * BCH + p) * 8 + srow;
    bg[p] = B + (size_t)(bn + row) * K + kbase + sg * 8;
  }
  auto stage = [&](int buf) {
    #pragma unroll
    for (int p = 0; p < 4; ++p) { gload16(ag[p], &lA[buf][(wave * 4 + p) * 512]); ag[p] += 64; }
    #pragma unroll
    for (int p = 0; p < BCH; ++p) { gload16(bg[p], &lB[buf][(wave * BCH + p) * 512]); bg[p] += 64; }
  };
  f32x4 acc[4][NI] = {};
  int nt = klen / 64;
  stage(0);
  __syncthreads();
  int cur = 0;
  int lrow = lane & 15, glq = lane >> 4;
  for (int t = 0; t < nt; ++t) {
    if (t + 1 < nt) stage(cur ^ 1);
    short8 bf[2][NI];
    #pragma unroll
    for (int kk = 0; kk < 2; ++kk)
      #pragma unroll
      for (int ni = 0; ni < NI; ++ni) {
        int row = wn * (BN / 2) + ni * 16 + lrow;
        int pg = (kk * 4 + glq) ^ (row & 7);
        bf[kk][ni] = *(const short8*)&lB[cur][row * 64 + pg * 8];
      }
    #pragma unroll
    for (int mi = 0; mi < 4; ++mi)
      #pragma unroll
      for (int kk = 0; kk < 2; ++kk) {
        int row = wm * 64 + mi * 16 + lrow;
        int pg = (kk * 4 + glq) ^ (row & 7);
        short8 af = *(const short8*)&lA[cur][row * 64 + pg * 8];
        #pragma unroll
        for (int ni = 0; ni < NI; ++ni)
          acc[mi][ni] = __builtin_amdgcn_mfma_f32_16x16x32_bf16(af, bf[kk][ni], acc[mi][ni], 0, 0, 0);
      }
    __syncthreads();
    cur ^= 1;
  }
  #pragma unroll
  for (int mi = 0; mi < 4; ++mi)
    #pragma unroll
    for (int ni = 0; ni < NI; ++ni) {
      int col = bn + wn * (BN / 2) + ni * 16 + lrow;
      float bv = 0.f;
      if (BIAS) bv = (col < 512) ? bias0[col] : bias1[col - 512];
      #pragma unroll
      for (int j = 0; j < 4; ++j) {
        int row = bm + wm * 64 + mi * 16 + glq * 4 + j;
        float vv = acc[mi][ni][j] + bv;
        if (CBF16) {
          unsigned short* C = (unsigned short*)Cv + (size_t)blockIdx.z * M * N;
          C[(size_t)row * N + col] = f2bf(vv);
        } else {
          float* C = (float*)Cv + (size_t)blockIdx.z * M * N;
          C[(size_t)row * N + col] = vv;
        }
      }
    }
}

// ---------------- counting sort of pairs by sub: hist -> prefix -> permute ----------------
__global__ __launch_bounds__(256) void k_hist(const int* __restrict__ pairs,
                                              int* __restrict__ hist) {
  int e = blockIdx.x * 256 + threadIdx.x;
  if (e < NPAIR) atomicAdd(&hist[pairs[2 * e]], 1);
}

__global__ __launch_bounds__(1024) void k_prefix(const int* __restrict__ hist,
                                                 int* __restrict__ offs) {
  __shared__ int s[1024];
  int t = threadIdx.x;
  int4 h = *(const int4*)&hist[t * 4];
  int loc = h.x + h.y + h.z + h.w;
  s[t] = loc;
  __syncthreads();
  for (int d = 1; d < 1024; d <<= 1) {
    int v = (t >= d) ? s[t - d] : 0;
    __syncthreads();
    s[t] += v;
    __syncthreads();
  }
  int base = (t > 0) ? s[t - 1] : 0;
  offs[t * 4]     = base;
  offs[t * 4 + 1] = base + h.x;
  offs[t * 4 + 2] = base + h.x + h.y;
  offs[t * 4 + 3] = base + h.x + h.y + h.z;
}

__global__ __launch_bounds__(256) void k_permute(const int* __restrict__ pairs,
                                                 int* __restrict__ offs,
                                                 int* __restrict__ perm) {
  int e = blockIdx.x * 256 + threadIdx.x;
  if (e < NPAIR) {
    int p = atomicAdd(&offs[pairs[2 * e]], 1);
    perm[p] = e;
  }
}

// ---------------- per-pair exp(score), sub-sorted order, XCD-chunked ----------------
// Sorted processing: each XCD works a contiguous sub-range -> Q rows L2-resident
// (~16x reuse); validity early-exit skips ~50% of gathers entirely.
__global__ __launch_bounds__(256) void k_scores(const unsigned short* __restrict__ QKb,
                                                const int* __restrict__ pairs,
                                                const int* __restrict__ perm,
                                                const float* __restrict__ agg,
                                                float* __restrict__ es,
                                                float* __restrict__ sumexp,
                                                int* __restrict__ scnt) {
  int wave = threadIdx.x >> 6, lane = threadIdx.x & 63;
  int nb = gridDim.x;
  int lin = blockIdx.x;
  int nch = nb >> 3;
  int nl = (lin & 7) * nch + (lin >> 3);   // XCD-chunked: contiguous perm range per XCD
  int e = perm[nl * 4 + wave];
  int2 pr = *(const int2*)&pairs[2 * e];
  int sub = pr.x, obj = pr.y;
  bool valid = (sub != obj) && (agg[(size_t)sub * N_INST + obj] != 0.f);
  if (!valid) {
    if (lane == 0) es[(size_t)e * 8] = -1.f;
    return;
  }
  short8 q8 = *(const short8*)&QKb[(size_t)sub * 1024 + lane * 8];
  short8 k8 = *(const short8*)&QKb[(size_t)obj * 1024 + 512 + lane * 8];
  float p = 0.f;
  #pragma unroll
  for (int j = 0; j < 8; ++j)
    p += bf2f((unsigned short)q8[j]) * bf2f((unsigned short)k8[j]);
  p += __shfl_xor(p, 1);
  p += __shfl_xor(p, 2);
  p += __shfl_xor(p, 4);
  float ev = expf(p * 0.125f);   // / sqrt(64)
  int h = lane >> 3;
  if ((lane & 7) == 0) {
    es[(size_t)e * 8 + h] = ev;
    atomicAdd(&sumexp[sub * 8 + h], ev);
  }
  if (lane == 0) atomicAdd(&scnt[sub], 1);
}

// ---------------- per-row denominators -> invden, base ----------------
__global__ __launch_bounds__(256) void k_denom(const float* __restrict__ sumexp,
                                               const int* __restrict__ scnt,
                                               const int* __restrict__ acnt,
                                               float* __restrict__ invden,
                                               float* __restrict__ base) {
  int i = blockIdx.x * 256 + threadIdx.x;
  if (i >= N_INST) return;
  float c0 = (float)(acnt[i] - scnt[i]);
  const float E0 = expf(1e-7f);
  float bsum = 0.f;
  #pragma unroll
  for (int h = 0; h < NHEAD; ++h) {
    float inv = 1.0f / (E0 + c0 + sumexp[i * NHEAD + h]);
    invden[i * NHEAD + h] = inv;
    bsum += inv;
  }
  base[i] = bsum * (1.0f / NHEAD);
}

// ---------------- scatter ratio entries into mask ----------------
__global__ __launch_bounds__(256) void k_scatter(const int* __restrict__ pairs,
                                                 const float* __restrict__ es,
                                                 const float* __restrict__ invden,
                                                 const float* __restrict__ base,
                                                 unsigned short* __restrict__ maskb) {
  int e = blockIdx.x * 256 + threadIdx.x;
  if (e >= NPAIR) return;
  float4 e0 = *(const float4*)&es[(size_t)e * 8];
  if (e0.x < 0.f) return;
  float4 e1 = *(const float4*)&es[(size_t)e * 8 + 4];
  int sub = pairs[2 * e], obj = pairs[2 * e + 1];
  const float* inv = &invden[sub * 8];
  float f = e0.x * inv[0] + e0.y * inv[1] + e0.z * inv[2] + e0.w * inv[3] +
            e1.x * inv[4] + e1.y * inv[5] + e1.z * inv[6] + e1.w * inv[7];
  maskb[(size_t)sub * N_INST + obj] = f2bf(f * 0.125f / base[sub]);
}

// ---------------- reduce split-K=4 bf16 partials + row scale ----------------
__global__ __launch_bounds__(256) void k_redscale(const unsigned short* __restrict__ P,
                                                  const float* __restrict__ base,
                                                  float* __restrict__ out) {
  size_t idx = ((size_t)blockIdx.x * 256 + threadIdx.x) * 4;
  int i = (int)(idx >> 9);
  const size_t S = (size_t)N_INST * 512;
  u16x4 a = *(const u16x4*)&P[idx];
  u16x4 b = *(const u16x4*)&P[idx + S];
  u16x4 c = *(const u16x4*)&P[idx + 2 * S];
  u16x4 d = *(const u16x4*)&P[idx + 3 * S];
  float s = base[i];
  float4 o;
  o.x = s * (bf2f(a[0]) + bf2f(b[0]) + bf2f(c[0]) + bf2f(d[0]));
  o.y = s * (bf2f(a[1]) + bf2f(b[1]) + bf2f(c[1]) + bf2f(d[1]));
  o.z = s * (bf2f(a[2]) + bf2f(b[2]) + bf2f(c[2]) + bf2f(d[2]));
  o.w = s * (bf2f(a[3]) + bf2f(b[3]) + bf2f(c[3]) + bf2f(d[3]));
  *(float4*)&out[idx] = o;
}

extern "C" void kernel_launch(void* const* d_in, const int* in_sizes, int n_in,
                              void* d_out, int out_size, void* d_ws, size_t ws_size,
                              hipStream_t stream) {
  const float* x   = (const float*)d_in[0];
  const float* agg = (const float*)d_in[1];
  const int*   prs = (const int*)d_in[2];
  const float* w_q = (const float*)d_in[3];
  const float* b_q = (const float*)d_in[4];
  const float* w_k = (const float*)d_in[5];
  const float* b_k = (const float*)d_in[6];
  float* out = (float*)d_out;

  char* ws = (char*)d_ws;
  size_t off = 0;
  auto alloc = [&](size_t bytes) -> void* {
    void* p = ws + off;
    off += (bytes + 255) & ~(size_t)255;
    return p;
  };
  unsigned short* xb    = (unsigned short*)alloc((size_t)N_INST * D_FEAT * 2);
  unsigned short* xbT   = (unsigned short*)alloc((size_t)D_FEAT * N_INST * 2);
  unsigned short* wqkb  = (unsigned short*)alloc((size_t)1024 * D_FEAT * 2);
  void*           QKP   = alloc((size_t)N_INST * 1024 * 2 > (size_t)N_INST * 512 * 2 * 4
                                ? (size_t)N_INST * 1024 * 2 * 2 : (size_t)N_INST * 512 * 2 * 4);
                                // 8MB QK bf16 table; reused as 4x bf16 partials (16MB) -> alloc 16MB
  float*          es    = (float*)alloc((size_t)NPAIR * NHEAD * 4);
  float*          sumexp= (float*)alloc((size_t)N_INST * NHEAD * 4);
  int*            scnt  = (int*)alloc((size_t)N_INST * 4);
  int*            acnt  = (int*)alloc((size_t)N_INST * 4);
  float*          invden= (float*)alloc((size_t)N_INST * NHEAD * 4);
  float*          base  = (float*)alloc((size_t)N_INST * 4);
  int*            hist  = (int*)alloc((size_t)N_INST * 4);
  int*            offs  = (int*)alloc((size_t)N_INST * 4);
  int*            perm  = (int*)alloc((size_t)NPAIR * 4);
  unsigned short* maskb = (unsigned short*)alloc((size_t)N_INST * N_INST * 2);

  hipMemsetAsync(sumexp, 0, (size_t)N_INST * NHEAD * 4, stream);
  hipMemsetAsync(scnt, 0, (size_t)N_INST * 4, stream);
  hipMemsetAsync(hist, 0, (size_t)N_INST * 4, stream);

  k_castw<<<dim3(D_FEAT * D_FEAT / 4 / 256, 2), 256, 0, stream>>>(w_q, w_k, wqkb);
  k_xprep<<<dim3(D_FEAT / 32, N_INST / 32), 256, 0, stream>>>(x, xb, xbT);
  k_hist<<<dim3(NPAIR / 256), 256, 0, stream>>>(prs, hist);
  k_prefix<<<dim3(1), 1024, 0, stream>>>(hist, offs);
  k_permute<<<dim3(NPAIR / 256), 256, 0, stream>>>(prs, offs, perm);
  k_mask_acnt<<<dim3(N_INST), 256, 0, stream>>>(agg, maskb, acnt);

  // fused Q|K projection: C (4096x1024 bf16) = xb (4096x512) * wqkb (1024x512)^T + bias
  k_gemm<1, 1, 64><<<dim3(1024 / 64, N_INST / 128, 1), 256, 0, stream>>>(
      xb, wqkb, b_q, b_k, QKP, N_INST, 1024, D_FEAT, D_FEAT);

  k_scores<<<dim3(NPAIR / 4), 256, 0, stream>>>((const unsigned short*)QKP, prs, perm, agg, es, sumexp, scnt);
  k_denom<<<dim3(N_INST / 256), 256, 0, stream>>>(sumexp, scnt, acnt, invden, base);
  k_scatter<<<dim3(NPAIR / 256), 256, 0, stream>>>(prs, es, invden, base, maskb);

  // bf16 partials = maskb (4096x4096) * xbT (512x4096)^T, 128x128 tile, split-K=4
  k_gemm<0, 1, 128><<<dim3(512 / 128, N_INST / 128, 4), 256, 0, stream>>>(
      maskb, xbT, nullptr, nullptr, QKP, N_INST, 512, N_INST, N_INST / 4);

  k_redscale<<<dim3(N_INST * 512 / 4 / 256), 256, 0, stream>>>((const unsigned short*)QKP, base, out);
}

// Round 11
// 150.381 us; speedup vs baseline: 1.1493x; 1.1493x over previous
//
#include <hip/hip_runtime.h>

#define N_INST 4096
#define D_FEAT 512
#define NHEAD 8
#define NPAIR 131072

typedef __attribute__((ext_vector_type(8))) short short8;
typedef __attribute__((ext_vector_type(4))) float f32x4;
typedef __attribute__((ext_vector_type(4))) unsigned short u16x4;

__device__ inline unsigned short f2bf(float f) {
  union { float f; unsigned u; } v; v.f = f;
  unsigned r = v.u + 0x7fffu + ((v.u >> 16) & 1u);
  return (unsigned short)(r >> 16);
}
__device__ inline float bf2f(unsigned short b) {
  union { unsigned u; float f; } v; v.u = ((unsigned)b) << 16; return v.f;
}
__device__ inline void gload16(const void* g, void* l) {
  __builtin_amdgcn_global_load_lds((const __attribute__((address_space(1))) unsigned int*)g,
                                   (__attribute__((address_space(3))) unsigned int*)l, 16, 0, 0);
}

// ---------------- both weight casts in one launch (y=0 -> w_q, y=1 -> w_k) ----------------
__global__ __launch_bounds__(256) void k_castw(const float* __restrict__ wq,
                                               const float* __restrict__ wk,
                                               unsigned short* __restrict__ dst) {
  const float* src = blockIdx.y ? wk : wq;
  unsigned short* d = dst + (size_t)blockIdx.y * D_FEAT * D_FEAT;
  int i = (blockIdx.x * 256 + threadIdx.x) * 4;
  float4 v = *(const float4*)&src[i];
  ushort4 o;
  o.x = f2bf(v.x); o.y = f2bf(v.y); o.z = f2bf(v.z); o.w = f2bf(v.w);
  *(ushort4*)&d[i] = o;
}

// ---------------- x (4096x512 f32) -> xb bf16 AND xT bf16 (512x4096), one read ----------------
__global__ __launch_bounds__(256) void k_xprep(const float* __restrict__ x,
                                               unsigned short* __restrict__ xb,
                                               unsigned short* __restrict__ xT) {
  __shared__ float t[32][33];
  int bx = blockIdx.x, by = blockIdx.y;
  int tx = threadIdx.x & 31, ty = threadIdx.x >> 5;
  #pragma unroll
  for (int r = 0; r < 4; ++r) {
    int row = by * 32 + ty + r * 8;
    float v = x[(size_t)row * D_FEAT + bx * 32 + tx];
    t[ty + r * 8][tx] = v;
    xb[(size_t)row * D_FEAT + bx * 32 + tx] = f2bf(v);
  }
  __syncthreads();
  #pragma unroll
  for (int r = 0; r < 4; ++r)
    xT[(size_t)(bx * 32 + ty + r * 8) * N_INST + by * 32 + tx] = f2bf(t[tx][ty + r * 8]);
}

// ---------------- block-per-row: 0/1 bf16 mask (diag=1) + off-diag count, NT streaming ----------------
__global__ __launch_bounds__(256) void k_mask_acnt(const float* __restrict__ agg,
                                                   unsigned short* __restrict__ maskb,
                                                   int* __restrict__ acnt) {
  int i = blockIdx.x;
  const f32x4* row = (const f32x4*)(agg + (size_t)i * N_INST);
  u16x4* mrow = (u16x4*)(maskb + (size_t)i * N_INST);
  int tid = threadIdx.x;
  f32x4 v[4];
  #pragma unroll
  for (int u = 0; u < 4; ++u)
    v[u] = __builtin_nontemporal_load(&row[u * 256 + tid]);
  int cnt = 0;
  #pragma unroll
  for (int u = 0; u < 4; ++u) {
    int t = u * 256 + tid;
    u16x4 m;
    m[0] = (v[u][0] != 0.f) ? 0x3F80 : 0;
    m[1] = (v[u][1] != 0.f) ? 0x3F80 : 0;
    m[2] = (v[u][2] != 0.f) ? 0x3F80 : 0;
    m[3] = (v[u][3] != 0.f) ? 0x3F80 : 0;
    cnt += (v[u][0] != 0.f) + (v[u][1] != 0.f) + (v[u][2] != 0.f) + (v[u][3] != 0.f);
    int j = t * 4;
    if (i >= j && i < j + 4) {
      int d = i - j;
      m[d] = 0x3F80;                    // diagonal always present
      cnt -= (v[u][d] != 0.f);          // diag not counted as generic
    }
    __builtin_nontemporal_store(m, &mrow[t]);
  }
  #pragma unroll
  for (int msk = 1; msk < 64; msk <<= 1) cnt += __shfl_xor(cnt, msk);
  __shared__ int wsum[4];
  if ((threadIdx.x & 63) == 0) wsum[threadIdx.x >> 6] = cnt;
  __syncthreads();
  if (threadIdx.x == 0) acnt[i] = wsum[0] + wsum[1] + wsum[2] + wsum[3];
}

// ---------------- NT bf16 MFMA GEMM, BM=128, BN templated (64 or 128), BK=64 ----------------
template<int BIAS, int CBF16, int BN>
__global__ __launch_bounds__(256, 2) void k_gemm(const unsigned short* __restrict__ A,
                                                 const unsigned short* __restrict__ B,
                                                 const float* __restrict__ bias0,
                                                 const float* __restrict__ bias1,
                                                 void* __restrict__ Cv,
                                                 int M, int N, int K, int klen) {
  constexpr int NI = BN / 32;
  constexpr int BCH = BN / 32;
  __shared__ __align__(16) unsigned short lA[2][128 * 64];
  __shared__ __align__(16) unsigned short lB[2][BN * 64];
  int tid = threadIdx.x, wave = tid >> 6, lane = tid & 63;
  int wm = wave & 1, wn = wave >> 1;
  int gx = gridDim.x;
  int nxy = gx * gridDim.y;
  int lin = blockIdx.x + gx * blockIdx.y;
  int nch = nxy >> 3;
  int nl = (lin & 7) * nch + (lin >> 3);
  int bx = nl % gx, by = nl / gx;
  int bm = by * 128, bn = bx * BN;
  int kbase = blockIdx.z * klen;
  int srow = lane >> 3;
  int sg = (lane & 7) ^ srow;
  const unsigned short* ag[4];
  const unsigned short* bg[BCH];
  #pragma unroll
  for (int p = 0; p < 4; ++p) {
    int row = (wave * 4 + p) * 8 + srow;
    ag[p] = A + (size_t)(bm + row) * K + kbase + sg * 8;
  }
  #pragma unroll
  for (int p = 0; p < BCH; ++p) {
    int row = (wave * BCH + p) * 8 + srow;
    bg[p] = B + (size_t)(bn + row) * K + kbase + sg * 8;
  }
  auto stage = [&](int buf) {
    #pragma unroll
    for (int p = 0; p < 4; ++p) { gload16(ag[p], &lA[buf][(wave * 4 + p) * 512]); ag[p] += 64; }
    #pragma unroll
    for (int p = 0; p < BCH; ++p) { gload16(bg[p], &lB[buf][(wave * BCH + p) * 512]); bg[p] += 64; }
  };
  f32x4 acc[4][NI] = {};
  int nt = klen / 64;
  stage(0);
  __syncthreads();
  int cur = 0;
  int lrow = lane & 15, glq = lane >> 4;
  for (int t = 0; t < nt; ++t) {
    if (t + 1 < nt) stage(cur ^ 1);
    short8 bf[2][NI];
    #pragma unroll
    for (int kk = 0; kk < 2; ++kk)
      #pragma unroll
      for (int ni = 0; ni < NI; ++ni) {
        int row = wn * (BN / 2) + ni * 16 + lrow;
        int pg = (kk * 4 + glq) ^ (row & 7);
        bf[kk][ni] = *(const short8*)&lB[cur][row * 64 + pg * 8];
      }
    #pragma unroll
    for (int mi = 0; mi < 4; ++mi)
      #pragma unroll
      for (int kk = 0; kk < 2; ++kk) {
        int row = wm * 64 + mi * 16 + lrow;
        int pg = (kk * 4 + glq) ^ (row & 7);
        short8 af = *(const short8*)&lA[cur][row * 64 + pg * 8];
        #pragma unroll
        for (int ni = 0; ni < NI; ++ni)
          acc[mi][ni] = __builtin_amdgcn_mfma_f32_16x16x32_bf16(af, bf[kk][ni], acc[mi][ni], 0, 0, 0);
      }
    __syncthreads();
    cur ^= 1;
  }
  #pragma unroll
  for (int mi = 0; mi < 4; ++mi)
    #pragma unroll
    for (int ni = 0; ni < NI; ++ni) {
      int col = bn + wn * (BN / 2) + ni * 16 + lrow;
      float bv = 0.f;
      if (BIAS) bv = (col < 512) ? bias0[col] : bias1[col - 512];
      #pragma unroll
      for (int j = 0; j < 4; ++j) {
        int row = bm + wm * 64 + mi * 16 + glq * 4 + j;
        float vv = acc[mi][ni][j] + bv;
        if (CBF16) {
          unsigned short* C = (unsigned short*)Cv + (size_t)blockIdx.z * M * N;
          C[(size_t)row * N + col] = f2bf(vv);
        } else {
          float* C = (float*)Cv + (size_t)blockIdx.z * M * N;
          C[(size_t)row * N + col] = vv;
        }
      }
    }
}

// ---------------- counting sort of pairs by sub: hist -> prefix -> permute ----------------
__global__ __launch_bounds__(256) void k_hist(const int* __restrict__ pairs,
                                              int* __restrict__ hist) {
  int e = blockIdx.x * 256 + threadIdx.x;
  if (e < NPAIR) atomicAdd(&hist[pairs[2 * e]], 1);
}

// writes BOTH offs (mutated by k_permute) and start (preserved for k_rowsum)
__global__ __launch_bounds__(1024) void k_prefix(const int* __restrict__ hist,
                                                 int* __restrict__ offs,
                                                 int* __restrict__ start) {
  __shared__ int s[1024];
  int t = threadIdx.x;
  int4 h = *(const int4*)&hist[t * 4];
  int loc = h.x + h.y + h.z + h.w;
  s[t] = loc;
  __syncthreads();
  for (int d = 1; d < 1024; d <<= 1) {
    int v = (t >= d) ? s[t - d] : 0;
    __syncthreads();
    s[t] += v;
    __syncthreads();
  }
  int base = (t > 0) ? s[t - 1] : 0;
  int o0 = base, o1 = base + h.x, o2 = o1 + h.y, o3 = o2 + h.z;
  offs[t * 4] = o0;     start[t * 4] = o0;
  offs[t * 4 + 1] = o1; start[t * 4 + 1] = o1;
  offs[t * 4 + 2] = o2; start[t * 4 + 2] = o2;
  offs[t * 4 + 3] = o3; start[t * 4 + 3] = o3;
}

__global__ __launch_bounds__(256) void k_permute(const int* __restrict__ pairs,
                                                 int* __restrict__ offs,
                                                 int* __restrict__ perm) {
  int e = blockIdx.x * 256 + threadIdx.x;
  if (e < NPAIR) {
    int p = atomicAdd(&offs[pairs[2 * e]], 1);
    perm[p] = e;
  }
}

// ---------------- per-pair exp(score): sorted gather, ZERO atomics ----------------
// Sorted+XCD-chunked: Q rows and agg rows L2-resident per XCD (R10: FETCH 87->33MB).
// R10 post-mortem: sumexp/scnt atomics from ~16 same-sub waves serialized (66us).
// Row sums now done contention-free in k_rowsum.
__global__ __launch_bounds__(256) void k_scores(const unsigned short* __restrict__ QKb,
                                                const int* __restrict__ pairs,
                                                const int* __restrict__ perm,
                                                const float* __restrict__ agg,
                                                float* __restrict__ es) {
  int wave = threadIdx.x >> 6, lane = threadIdx.x & 63;
  int nb = gridDim.x;
  int lin = blockIdx.x;
  int nch = nb >> 3;
  int nl = (lin & 7) * nch + (lin >> 3);   // XCD-chunked contiguous perm range
  int e = perm[nl * 4 + wave];
  int2 pr = *(const int2*)&pairs[2 * e];
  int sub = pr.x, obj = pr.y;
  bool valid = (sub != obj) && (agg[(size_t)sub * N_INST + obj] != 0.f);
  if (!valid) {
    if (lane == 0) es[(size_t)e * 8] = -1.f;
    return;
  }
  short8 q8 = *(const short8*)&QKb[(size_t)sub * 1024 + lane * 8];
  short8 k8 = *(const short8*)&QKb[(size_t)obj * 1024 + 512 + lane * 8];
  float p = 0.f;
  #pragma unroll
  for (int j = 0; j < 8; ++j)
    p += bf2f((unsigned short)q8[j]) * bf2f((unsigned short)k8[j]);
  p += __shfl_xor(p, 1);
  p += __shfl_xor(p, 2);
  p += __shfl_xor(p, 4);
  float ev = expf(p * 0.125f);   // / sqrt(64)
  if ((lane & 7) == 0)
    es[(size_t)e * 8 + (lane >> 3)] = ev;
}

// ---------------- wave-per-row segmented reduction: sumexp+denom fused, no atomics ----------------
// lane = g*8+h: 8 pair-groups x 8 heads; reduce over g (xor 8/16/32), then heads.
__global__ __launch_bounds__(256) void k_rowsum(const float* __restrict__ es,
                                                const int* __restrict__ perm,
                                                const int* __restrict__ start,
                                                const int* __restrict__ hist,
                                                const int* __restrict__ acnt,
                                                float* __restrict__ invden,
                                                float* __restrict__ base) {
  int row = blockIdx.x * 4 + (threadIdx.x >> 6);
  int lane = threadIdx.x & 63;
  int g = lane >> 3, h = lane & 7;
  int s0 = start[row], n = hist[row];
  float sum = 0.f;
  int vcnt = 0;
  for (int j = g; j < n; j += 8) {
    int e = perm[s0 + j];
    float v0 = es[(size_t)e * 8];
    if (v0 >= 0.f) {
      sum += es[(size_t)e * 8 + h];
      vcnt += (h == 0);
    }
  }
  sum += __shfl_xor(sum, 8);  sum += __shfl_xor(sum, 16);  sum += __shfl_xor(sum, 32);
  vcnt += __shfl_xor(vcnt, 8); vcnt += __shfl_xor(vcnt, 16); vcnt += __shfl_xor(vcnt, 32);
  vcnt += __shfl_xor(vcnt, 1); vcnt += __shfl_xor(vcnt, 2); vcnt += __shfl_xor(vcnt, 4);
  if (lane < 8) {
    float c0 = (float)(acnt[row] - vcnt);
    const float E0 = expf(1e-7f);
    float inv = 1.0f / (E0 + c0 + sum);
    invden[row * 8 + lane] = inv;
    float bsum = inv;
    bsum += __shfl_xor(bsum, 1); bsum += __shfl_xor(bsum, 2); bsum += __shfl_xor(bsum, 4);
    if (lane == 0) base[row] = bsum * (1.0f / NHEAD);
  }
}

// ---------------- scatter ratio entries into mask ----------------
__global__ __launch_bounds__(256) void k_scatter(const int* __restrict__ pairs,
                                                 const float* __restrict__ es,
                                                 const float* __restrict__ invden,
                                                 const float* __restrict__ base,
                                                 unsigned short* __restrict__ maskb) {
  int e = blockIdx.x * 256 + threadIdx.x;
  if (e >= NPAIR) return;
  float4 e0 = *(const float4*)&es[(size_t)e * 8];
  if (e0.x < 0.f) return;
  float4 e1 = *(const float4*)&es[(size_t)e * 8 + 4];
  int sub = pairs[2 * e], obj = pairs[2 * e + 1];
  const float* inv = &invden[sub * 8];
  float f = e0.x * inv[0] + e0.y * inv[1] + e0.z * inv[2] + e0.w * inv[3] +
            e1.x * inv[4] + e1.y * inv[5] + e1.z * inv[6] + e1.w * inv[7];
  maskb[(size_t)sub * N_INST + obj] = f2bf(f * 0.125f / base[sub]);
}

// ---------------- reduce split-K=4 bf16 partials + row scale ----------------
__global__ __launch_bounds__(256) void k_redscale(const unsigned short* __restrict__ P,
                                                  const float* __restrict__ base,
                                                  float* __restrict__ out) {
  size_t idx = ((size_t)blockIdx.x * 256 + threadIdx.x) * 4;
  int i = (int)(idx >> 9);
  const size_t S = (size_t)N_INST * 512;
  u16x4 a = *(const u16x4*)&P[idx];
  u16x4 b = *(const u16x4*)&P[idx + S];
  u16x4 c = *(const u16x4*)&P[idx + 2 * S];
  u16x4 d = *(const u16x4*)&P[idx + 3 * S];
  float s = base[i];
  float4 o;
  o.x = s * (bf2f(a[0]) + bf2f(b[0]) + bf2f(c[0]) + bf2f(d[0]));
  o.y = s * (bf2f(a[1]) + bf2f(b[1]) + bf2f(c[1]) + bf2f(d[1]));
  o.z = s * (bf2f(a[2]) + bf2f(b[2]) + bf2f(c[2]) + bf2f(d[2]));
  o.w = s * (bf2f(a[3]) + bf2f(b[3]) + bf2f(c[3]) + bf2f(d[3]));
  *(float4*)&out[idx] = o;
}

extern "C" void kernel_launch(void* const* d_in, const int* in_sizes, int n_in,
                              void* d_out, int out_size, void* d_ws, size_t ws_size,
                              hipStream_t stream) {
  const float* x   = (const float*)d_in[0];
  const float* agg = (const float*)d_in[1];
  const int*   prs = (const int*)d_in[2];
  const float* w_q = (const float*)d_in[3];
  const float* b_q = (const float*)d_in[4];
  const float* w_k = (const float*)d_in[5];
  const float* b_k = (const float*)d_in[6];
  float* out = (float*)d_out;

  char* ws = (char*)d_ws;
  size_t off = 0;
  auto alloc = [&](size_t bytes) -> void* {
    void* p = ws + off;
    off += (bytes + 255) & ~(size_t)255;
    return p;
  };
  unsigned short* xb    = (unsigned short*)alloc((size_t)N_INST * D_FEAT * 2);
  unsigned short* xbT   = (unsigned short*)alloc((size_t)D_FEAT * N_INST * 2);
  unsigned short* wqkb  = (unsigned short*)alloc((size_t)1024 * D_FEAT * 2);
  void*           QKP   = alloc((size_t)N_INST * 512 * 2 * 4);  // 8MB QK bf16 table; reused as 4x bf16 partials (16MB)
  float*          es    = (float*)alloc((size_t)NPAIR * NHEAD * 4);
  int*            acnt  = (int*)alloc((size_t)N_INST * 4);
  float*          invden= (float*)alloc((size_t)N_INST * NHEAD * 4);
  float*          base  = (float*)alloc((size_t)N_INST * 4);
  int*            hist  = (int*)alloc((size_t)N_INST * 4);
  int*            offs  = (int*)alloc((size_t)N_INST * 4);
  int*            start = (int*)alloc((size_t)N_INST * 4);
  int*            perm  = (int*)alloc((size_t)NPAIR * 4);
  unsigned short* maskb = (unsigned short*)alloc((size_t)N_INST * N_INST * 2);

  hipMemsetAsync(hist, 0, (size_t)N_INST * 4, stream);

  k_castw<<<dim3(D_FEAT * D_FEAT / 4 / 256, 2), 256, 0, stream>>>(w_q, w_k, wqkb);
  k_xprep<<<dim3(D_FEAT / 32, N_INST / 32), 256, 0, stream>>>(x, xb, xbT);
  k_hist<<<dim3(NPAIR / 256), 256, 0, stream>>>(prs, hist);
  k_prefix<<<dim3(1), 1024, 0, stream>>>(hist, offs, start);
  k_permute<<<dim3(NPAIR / 256), 256, 0, stream>>>(prs, offs, perm);
  k_mask_acnt<<<dim3(N_INST), 256, 0, stream>>>(agg, maskb, acnt);

  // fused Q|K projection: C (4096x1024 bf16) = xb (4096x512) * wqkb (1024x512)^T + bias
  k_gemm<1, 1, 64><<<dim3(1024 / 64, N_INST / 128, 1), 256, 0, stream>>>(
      xb, wqkb, b_q, b_k, QKP, N_INST, 1024, D_FEAT, D_FEAT);

  k_scores<<<dim3(NPAIR / 4), 256, 0, stream>>>((const unsigned short*)QKP, prs, perm, agg, es);
  k_rowsum<<<dim3(N_INST / 4), 256, 0, stream>>>(es, perm, start, hist, acnt, invden, base);
  k_scatter<<<dim3(NPAIR / 256), 256, 0, stream>>>(prs, es, invden, base, maskb);

  // bf16 partials = maskb (4096x4096) * xbT (512x4096)^T, 128x128 tile, split-K=4
  k_gemm<0, 1, 128><<<dim3(512 / 128, N_INST / 128, 4), 256, 0, stream>>>(
      maskb, xbT, nullptr, nullptr, QKP, N_INST, 512, N_INST, N_INST / 4);

  k_redscale<<<dim3(N_INST * 512 / 4 / 256), 256, 0, stream>>>((const unsigned short*)QKP, base, out);
}

// Round 12
// 125.247 us; speedup vs baseline: 1.3799x; 1.2007x over previous
//
#include <hip/hip_runtime.h>

#define N_INST 4096
#define D_FEAT 512
#define NHEAD 8
#define NPAIR 131072

typedef __attribute__((ext_vector_type(8))) short short8;
typedef __attribute__((ext_vector_type(4))) float f32x4;
typedef __attribute__((ext_vector_type(4))) unsigned short u16x4;

__device__ inline unsigned short f2bf(float f) {
  union { float f; unsigned u; } v; v.f = f;
  unsigned r = v.u + 0x7fffu + ((v.u >> 16) & 1u);
  return (unsigned short)(r >> 16);
}
__device__ inline float bf2f(unsigned short b) {
  union { unsigned u; float f; } v; v.u = ((unsigned)b) << 16; return v.f;
}
__device__ inline void gload16(const void* g, void* l) {
  __builtin_amdgcn_global_load_lds((const __attribute__((address_space(1))) unsigned int*)g,
                                   (__attribute__((address_space(3))) unsigned int*)l, 16, 0, 0);
}

// ---------------- both weight casts in one launch (y=0 -> w_q, y=1 -> w_k) ----------------
__global__ __launch_bounds__(256) void k_castw(const float* __restrict__ wq,
                                               const float* __restrict__ wk,
                                               unsigned short* __restrict__ dst) {
  const float* src = blockIdx.y ? wk : wq;
  unsigned short* d = dst + (size_t)blockIdx.y * D_FEAT * D_FEAT;
  int i = (blockIdx.x * 256 + threadIdx.x) * 4;
  float4 v = *(const float4*)&src[i];
  ushort4 o;
  o.x = f2bf(v.x); o.y = f2bf(v.y); o.z = f2bf(v.z); o.w = f2bf(v.w);
  *(ushort4*)&d[i] = o;
}

// ---------------- x (4096x512 f32) -> xb bf16 AND xT bf16 (512x4096), one read ----------------
__global__ __launch_bounds__(256) void k_xprep(const float* __restrict__ x,
                                               unsigned short* __restrict__ xb,
                                               unsigned short* __restrict__ xT) {
  __shared__ float t[32][33];
  int bx = blockIdx.x, by = blockIdx.y;
  int tx = threadIdx.x & 31, ty = threadIdx.x >> 5;
  #pragma unroll
  for (int r = 0; r < 4; ++r) {
    int row = by * 32 + ty + r * 8;
    float v = x[(size_t)row * D_FEAT + bx * 32 + tx];
    t[ty + r * 8][tx] = v;
    xb[(size_t)row * D_FEAT + bx * 32 + tx] = f2bf(v);
  }
  __syncthreads();
  #pragma unroll
  for (int r = 0; r < 4; ++r)
    xT[(size_t)(bx * 32 + ty + r * 8) * N_INST + by * 32 + tx] = f2bf(t[tx][ty + r * 8]);
}

// ---------------- block-per-row: 0/1 bf16 mask (diag=1) + off-diag count, NT streaming ----------------
__global__ __launch_bounds__(256) void k_mask_acnt(const float* __restrict__ agg,
                                                   unsigned short* __restrict__ maskb,
                                                   int* __restrict__ acnt) {
  int i = blockIdx.x;
  const f32x4* row = (const f32x4*)(agg + (size_t)i * N_INST);
  u16x4* mrow = (u16x4*)(maskb + (size_t)i * N_INST);
  int tid = threadIdx.x;
  f32x4 v[4];
  #pragma unroll
  for (int u = 0; u < 4; ++u)
    v[u] = __builtin_nontemporal_load(&row[u * 256 + tid]);
  int cnt = 0;
  #pragma unroll
  for (int u = 0; u < 4; ++u) {
    int t = u * 256 + tid;
    u16x4 m;
    m[0] = (v[u][0] != 0.f) ? 0x3F80 : 0;
    m[1] = (v[u][1] != 0.f) ? 0x3F80 : 0;
    m[2] = (v[u][2] != 0.f) ? 0x3F80 : 0;
    m[3] = (v[u][3] != 0.f) ? 0x3F80 : 0;
    cnt += (v[u][0] != 0.f) + (v[u][1] != 0.f) + (v[u][2] != 0.f) + (v[u][3] != 0.f);
    int j = t * 4;
    if (i >= j && i < j + 4) {
      int d = i - j;
      m[d] = 0x3F80;                    // diagonal always present
      cnt -= (v[u][d] != 0.f);          // diag not counted as generic
    }
    __builtin_nontemporal_store(m, &mrow[t]);
  }
  #pragma unroll
  for (int msk = 1; msk < 64; msk <<= 1) cnt += __shfl_xor(cnt, msk);
  __shared__ int wsum[4];
  if ((threadIdx.x & 63) == 0) wsum[threadIdx.x >> 6] = cnt;
  __syncthreads();
  if (threadIdx.x == 0) acnt[i] = wsum[0] + wsum[1] + wsum[2] + wsum[3];
}

// ---------------- NT bf16 MFMA GEMM, BM=128, BN templated (64 or 128), BK=64 ----------------
template<int BIAS, int CBF16, int BN>
__global__ __launch_bounds__(256, 2) void k_gemm(const unsigned short* __restrict__ A,
                                                 const unsigned short* __restrict__ B,
                                                 const float* __restrict__ bias0,
                                                 const float* __restrict__ bias1,
                                                 void* __restrict__ Cv,
                                                 int M, int N, int K, int klen) {
  constexpr int NI = BN / 32;
  constexpr int BCH = BN / 32;
  __shared__ __align__(16) unsigned short lA[2][128 * 64];
  __shared__ __align__(16) unsigned short lB[2][BN * 64];
  int tid = threadIdx.x, wave = tid >> 6, lane = tid & 63;
  int wm = wave & 1, wn = wave >> 1;
  int gx = gridDim.x;
  int nxy = gx * gridDim.y;
  int lin = blockIdx.x + gx * blockIdx.y;
  int nch = nxy >> 3;
  int nl = (lin & 7) * nch + (lin >> 3);
  int bx = nl % gx, by = nl / gx;
  int bm = by * 128, bn = bx * BN;
  int kbase = blockIdx.z * klen;
  int srow = lane >> 3;
  int sg = (lane & 7) ^ srow;
  const unsigned short* ag[4];
  const unsigned short* bg[BCH];
  #pragma unroll
  for (int p = 0; p < 4; ++p) {
    int row = (wave * 4 + p) * 8 + srow;
    ag[p] = A + (size_t)(bm + row) * K + kbase + sg * 8;
  }
  #pragma unroll
  for (int p = 0; p < BCH; ++p) {
    int row = (wave * BCH + p) * 8 + srow;
    bg[p] = B + (size_t)(bn + row) * K + kbase + sg * 8;
  }
  auto stage = [&](int buf) {
    #pragma unroll
    for (int p = 0; p < 4; ++p) { gload16(ag[p], &lA[buf][(wave * 4 + p) * 512]); ag[p] += 64; }
    #pragma unroll
    for (int p = 0; p < BCH; ++p) { gload16(bg[p], &lB[buf][(wave * BCH + p) * 512]); bg[p] += 64; }
  };
  f32x4 acc[4][NI] = {};
  int nt = klen / 64;
  stage(0);
  __syncthreads();
  int cur = 0;
  int lrow = lane & 15, glq = lane >> 4;
  for (int t = 0; t < nt; ++t) {
    if (t + 1 < nt) stage(cur ^ 1);
    short8 bf[2][NI];
    #pragma unroll
    for (int kk = 0; kk < 2; ++kk)
      #pragma unroll
      for (int ni = 0; ni < NI; ++ni) {
        int row = wn * (BN / 2) + ni * 16 + lrow;
        int pg = (kk * 4 + glq) ^ (row & 7);
        bf[kk][ni] = *(const short8*)&lB[cur][row * 64 + pg * 8];
      }
    #pragma unroll
    for (int mi = 0; mi < 4; ++mi)
      #pragma unroll
      for (int kk = 0; kk < 2; ++kk) {
        int row = wm * 64 + mi * 16 + lrow;
        int pg = (kk * 4 + glq) ^ (row & 7);
        short8 af = *(const short8*)&lA[cur][row * 64 + pg * 8];
        #pragma unroll
        for (int ni = 0; ni < NI; ++ni)
          acc[mi][ni] = __builtin_amdgcn_mfma_f32_16x16x32_bf16(af, bf[kk][ni], acc[mi][ni], 0, 0, 0);
      }
    __syncthreads();
    cur ^= 1;
  }
  #pragma unroll
  for (int mi = 0; mi < 4; ++mi)
    #pragma unroll
    for (int ni = 0; ni < NI; ++ni) {
      int col = bn + wn * (BN / 2) + ni * 16 + lrow;
      float bv = 0.f;
      if (BIAS) bv = (col < 512) ? bias0[col] : bias1[col - 512];
      #pragma unroll
      for (int j = 0; j < 4; ++j) {
        int row = bm + wm * 64 + mi * 16 + glq * 4 + j;
        float vv = acc[mi][ni][j] + bv;
        if (CBF16) {
          unsigned short* C = (unsigned short*)Cv + (size_t)blockIdx.z * M * N;
          C[(size_t)row * N + col] = f2bf(vv);
        } else {
          float* C = (float*)Cv + (size_t)blockIdx.z * M * N;
          C[(size_t)row * N + col] = vv;
        }
      }
    }
}

// ---------------- per-pair exp(score): 8 pairs/wave batched gather (MLP), random order ----------------
// R11 post-mortem: 1 pair/wave = 4-deep dependent chain, latency-bound (VGPR=12).
// Batch 8 pairs: 8 descriptor loads, 8 validity loads, then up to 16 q/k gathers
// all in flight before any use. Atomics at random pair order = low contention (R9: proven).
__global__ __launch_bounds__(256) void k_scores(const unsigned short* __restrict__ QKb,
                                                const int* __restrict__ pairs,
                                                const float* __restrict__ agg,
                                                float* __restrict__ es,
                                                float* __restrict__ sumexp,
                                                int* __restrict__ scnt) {
  int wave = threadIdx.x >> 6, lane = threadIdx.x & 63;
  int ebase = (blockIdx.x * 4 + wave) * 8;
  int subs[8], objs[8];
  #pragma unroll
  for (int u = 0; u < 8; ++u) {
    int2 pr = *(const int2*)&pairs[2 * (ebase + u)];
    subs[u] = pr.x; objs[u] = pr.y;
  }
  bool val[8];
  #pragma unroll
  for (int u = 0; u < 8; ++u)
    val[u] = (subs[u] != objs[u]) && (agg[(size_t)subs[u] * N_INST + objs[u]] != 0.f);
  short8 q8[8], k8[8];
  #pragma unroll
  for (int u = 0; u < 8; ++u) {
    if (val[u]) {
      q8[u] = *(const short8*)&QKb[(size_t)subs[u] * 1024 + lane * 8];
      k8[u] = *(const short8*)&QKb[(size_t)objs[u] * 1024 + 512 + lane * 8];
    }
  }
  #pragma unroll
  for (int u = 0; u < 8; ++u) {
    if (!val[u]) {
      if (lane == 0) es[(size_t)(ebase + u) * 8] = -1.f;
      continue;
    }
    float p = 0.f;
    #pragma unroll
    for (int j = 0; j < 8; ++j)
      p += bf2f((unsigned short)q8[u][j]) * bf2f((unsigned short)k8[u][j]);
    p += __shfl_xor(p, 1);
    p += __shfl_xor(p, 2);
    p += __shfl_xor(p, 4);
    float ev = expf(p * 0.125f);   // / sqrt(64)
    if ((lane & 7) == 0) {
      int h = lane >> 3;
      es[(size_t)(ebase + u) * 8 + h] = ev;
      atomicAdd(&sumexp[subs[u] * 8 + h], ev);
    }
    if (lane == 0) atomicAdd(&scnt[subs[u]], 1);
  }
}

// ---------------- per-row denominators -> invden, base ----------------
__global__ __launch_bounds__(256) void k_denom(const float* __restrict__ sumexp,
                                               const int* __restrict__ scnt,
                                               const int* __restrict__ acnt,
                                               float* __restrict__ invden,
                                               float* __restrict__ base) {
  int i = blockIdx.x * 256 + threadIdx.x;
  if (i >= N_INST) return;
  float c0 = (float)(acnt[i] - scnt[i]);
  const float E0 = expf(1e-7f);
  float bsum = 0.f;
  #pragma unroll
  for (int h = 0; h < NHEAD; ++h) {
    float inv = 1.0f / (E0 + c0 + sumexp[i * NHEAD + h]);
    invden[i * NHEAD + h] = inv;
    bsum += inv;
  }
  base[i] = bsum * (1.0f / NHEAD);
}

// ---------------- scatter ratio entries into mask ----------------
__global__ __launch_bounds__(256) void k_scatter(const int* __restrict__ pairs,
                                                 const float* __restrict__ es,
                                                 const float* __restrict__ invden,
                                                 const float* __restrict__ base,
                                                 unsigned short* __restrict__ maskb) {
  int e = blockIdx.x * 256 + threadIdx.x;
  if (e >= NPAIR) return;
  float4 e0 = *(const float4*)&es[(size_t)e * 8];
  if (e0.x < 0.f) return;
  float4 e1 = *(const float4*)&es[(size_t)e * 8 + 4];
  int sub = pairs[2 * e], obj = pairs[2 * e + 1];
  const float* inv = &invden[sub * 8];
  float f = e0.x * inv[0] + e0.y * inv[1] + e0.z * inv[2] + e0.w * inv[3] +
            e1.x * inv[4] + e1.y * inv[5] + e1.z * inv[6] + e1.w * inv[7];
  maskb[(size_t)sub * N_INST + obj] = f2bf(f * 0.125f / base[sub]);
}

// ---------------- reduce split-K=4 bf16 partials + row scale ----------------
__global__ __launch_bounds__(256) void k_redscale(const unsigned short* __restrict__ P,
                                                  const float* __restrict__ base,
                                                  float* __restrict__ out) {
  size_t idx = ((size_t)blockIdx.x * 256 + threadIdx.x) * 4;
  int i = (int)(idx >> 9);
  const size_t S = (size_t)N_INST * 512;
  u16x4 a = *(const u16x4*)&P[idx];
  u16x4 b = *(const u16x4*)&P[idx + S];
  u16x4 c = *(const u16x4*)&P[idx + 2 * S];
  u16x4 d = *(const u16x4*)&P[idx + 3 * S];
  float s = base[i];
  float4 o;
  o.x = s * (bf2f(a[0]) + bf2f(b[0]) + bf2f(c[0]) + bf2f(d[0]));
  o.y = s * (bf2f(a[1]) + bf2f(b[1]) + bf2f(c[1]) + bf2f(d[1]));
  o.z = s * (bf2f(a[2]) + bf2f(b[2]) + bf2f(c[2]) + bf2f(d[2]));
  o.w = s * (bf2f(a[3]) + bf2f(b[3]) + bf2f(c[3]) + bf2f(d[3]));
  *(float4*)&out[idx] = o;
}

extern "C" void kernel_launch(void* const* d_in, const int* in_sizes, int n_in,
                              void* d_out, int out_size, void* d_ws, size_t ws_size,
                              hipStream_t stream) {
  const float* x   = (const float*)d_in[0];
  const float* agg = (const float*)d_in[1];
  const int*   prs = (const int*)d_in[2];
  const float* w_q = (const float*)d_in[3];
  const float* b_q = (const float*)d_in[4];
  const float* w_k = (const float*)d_in[5];
  const float* b_k = (const float*)d_in[6];
  float* out = (float*)d_out;

  char* ws = (char*)d_ws;
  size_t off = 0;
  auto alloc = [&](size_t bytes) -> void* {
    void* p = ws + off;
    off += (bytes + 255) & ~(size_t)255;
    return p;
  };
  unsigned short* xb    = (unsigned short*)alloc((size_t)N_INST * D_FEAT * 2);
  unsigned short* xbT   = (unsigned short*)alloc((size_t)D_FEAT * N_INST * 2);
  unsigned short* wqkb  = (unsigned short*)alloc((size_t)1024 * D_FEAT * 2);
  void*           QKP   = alloc((size_t)N_INST * 512 * 2 * 4);  // 8MB QK bf16 table; reused as 4x bf16 partials (16MB)
  float*          es    = (float*)alloc((size_t)NPAIR * NHEAD * 4);
  float*          sumexp= (float*)alloc((size_t)N_INST * NHEAD * 4);
  int*            scnt  = (int*)alloc((size_t)N_INST * 4);
  int*            acnt  = (int*)alloc((size_t)N_INST * 4);
  float*          invden= (float*)alloc((size_t)N_INST * NHEAD * 4);
  float*          base  = (float*)alloc((size_t)N_INST * 4);
  unsigned short* maskb = (unsigned short*)alloc((size_t)N_INST * N_INST * 2);

  hipMemsetAsync(sumexp, 0, (size_t)N_INST * NHEAD * 4, stream);
  hipMemsetAsync(scnt, 0, (size_t)N_INST * 4, stream);

  k_castw<<<dim3(D_FEAT * D_FEAT / 4 / 256, 2), 256, 0, stream>>>(w_q, w_k, wqkb);
  k_xprep<<<dim3(D_FEAT / 32, N_INST / 32), 256, 0, stream>>>(x, xb, xbT);
  k_mask_acnt<<<dim3(N_INST), 256, 0, stream>>>(agg, maskb, acnt);

  // fused Q|K projection: C (4096x1024 bf16) = xb (4096x512) * wqkb (1024x512)^T + bias
  k_gemm<1, 1, 64><<<dim3(1024 / 64, N_INST / 128, 1), 256, 0, stream>>>(
      xb, wqkb, b_q, b_k, QKP, N_INST, 1024, D_FEAT, D_FEAT);

  k_scores<<<dim3(NPAIR / 32), 256, 0, stream>>>((const unsigned short*)QKP, prs, agg, es, sumexp, scnt);
  k_denom<<<dim3(N_INST / 256), 256, 0, stream>>>(sumexp, scnt, acnt, invden, base);
  k_scatter<<<dim3(NPAIR / 256), 256, 0, stream>>>(prs, es, invden, base, maskb);

  // bf16 partials = maskb (4096x4096) * xbT (512x4096)^T, 128x128 tile, split-K=4
  k_gemm<0, 1, 128><<<dim3(512 / 128, N_INST / 128, 4), 256, 0, stream>>>(
      maskb, xbT, nullptr, nullptr, QKP, N_INST, 512, N_INST, N_INST / 4);

  k_redscale<<<dim3(N_INST * 512 / 4 / 256), 256, 0, stream>>>((const unsigned short*)QKP, base, out);
}

// Round 13
// 117.700 us; speedup vs baseline: 1.4684x; 1.0641x over previous
//
#include <hip/hip_runtime.h>

#define N_INST 4096
#define D_FEAT 512
#define NHEAD 8
#define NPAIR 131072

typedef __attribute__((ext_vector_type(8))) short short8;
typedef __attribute__((ext_vector_type(4))) float f32x4;
typedef __attribute__((ext_vector_type(4))) unsigned short u16x4;

__device__ inline unsigned short f2bf(float f) {
  union { float f; unsigned u; } v; v.f = f;
  unsigned r = v.u + 0x7fffu + ((v.u >> 16) & 1u);
  return (unsigned short)(r >> 16);
}
__device__ inline float bf2f(unsigned short b) {
  union { unsigned u; float f; } v; v.u = ((unsigned)b) << 16; return v.f;
}
__device__ inline void gload16(const void* g, void* l) {
  __builtin_amdgcn_global_load_lds((const __attribute__((address_space(1))) unsigned int*)g,
                                   (__attribute__((address_space(3))) unsigned int*)l, 16, 0, 0);
}

// ---------------- both weight casts in one launch (y=0 -> w_q, y=1 -> w_k) ----------------
__global__ __launch_bounds__(256) void k_castw(const float* __restrict__ wq,
                                               const float* __restrict__ wk,
                                               unsigned short* __restrict__ dst) {
  const float* src = blockIdx.y ? wk : wq;
  unsigned short* d = dst + (size_t)blockIdx.y * D_FEAT * D_FEAT;
  int i = (blockIdx.x * 256 + threadIdx.x) * 4;
  float4 v = *(const float4*)&src[i];
  ushort4 o;
  o.x = f2bf(v.x); o.y = f2bf(v.y); o.z = f2bf(v.z); o.w = f2bf(v.w);
  *(ushort4*)&d[i] = o;
}

// ---------------- x (4096x512 f32) -> xb bf16 AND xT bf16 (512x4096), one read ----------------
__global__ __launch_bounds__(256) void k_xprep(const float* __restrict__ x,
                                               unsigned short* __restrict__ xb,
                                               unsigned short* __restrict__ xT) {
  __shared__ float t[32][33];
  int bx = blockIdx.x, by = blockIdx.y;
  int tx = threadIdx.x & 31, ty = threadIdx.x >> 5;
  #pragma unroll
  for (int r = 0; r < 4; ++r) {
    int row = by * 32 + ty + r * 8;
    float v = x[(size_t)row * D_FEAT + bx * 32 + tx];
    t[ty + r * 8][tx] = v;
    xb[(size_t)row * D_FEAT + bx * 32 + tx] = f2bf(v);
  }
  __syncthreads();
  #pragma unroll
  for (int r = 0; r < 4; ++r)
    xT[(size_t)(bx * 32 + ty + r * 8) * N_INST + by * 32 + tx] = f2bf(t[tx][ty + r * 8]);
}

// ---------------- block-per-row: 0/1 bf16 mask (diag=1) + off-diag count, NT streaming ----------------
__global__ __launch_bounds__(256) void k_mask_acnt(const float* __restrict__ agg,
                                                   unsigned short* __restrict__ maskb,
                                                   int* __restrict__ acnt) {
  int i = blockIdx.x;
  const f32x4* row = (const f32x4*)(agg + (size_t)i * N_INST);
  u16x4* mrow = (u16x4*)(maskb + (size_t)i * N_INST);
  int tid = threadIdx.x;
  f32x4 v[4];
  #pragma unroll
  for (int u = 0; u < 4; ++u)
    v[u] = __builtin_nontemporal_load(&row[u * 256 + tid]);
  int cnt = 0;
  #pragma unroll
  for (int u = 0; u < 4; ++u) {
    int t = u * 256 + tid;
    u16x4 m;
    m[0] = (v[u][0] != 0.f) ? 0x3F80 : 0;
    m[1] = (v[u][1] != 0.f) ? 0x3F80 : 0;
    m[2] = (v[u][2] != 0.f) ? 0x3F80 : 0;
    m[3] = (v[u][3] != 0.f) ? 0x3F80 : 0;
    cnt += (v[u][0] != 0.f) + (v[u][1] != 0.f) + (v[u][2] != 0.f) + (v[u][3] != 0.f);
    int j = t * 4;
    if (i >= j && i < j + 4) {
      int d = i - j;
      m[d] = 0x3F80;                    // diagonal always present
      cnt -= (v[u][d] != 0.f);          // diag not counted as generic
    }
    __builtin_nontemporal_store(m, &mrow[t]);
  }
  #pragma unroll
  for (int msk = 1; msk < 64; msk <<= 1) cnt += __shfl_xor(cnt, msk);
  __shared__ int wsum[4];
  if ((threadIdx.x & 63) == 0) wsum[threadIdx.x >> 6] = cnt;
  __syncthreads();
  if (threadIdx.x == 0) acnt[i] = wsum[0] + wsum[1] + wsum[2] + wsum[3];
}

// ---------------- NT bf16 MFMA GEMM, BM=128, BN templated (64 or 128), BK=64 ----------------
template<int BIAS, int CBF16, int BN>
__global__ __launch_bounds__(256, 2) void k_gemm(const unsigned short* __restrict__ A,
                                                 const unsigned short* __restrict__ B,
                                                 const float* __restrict__ bias0,
                                                 const float* __restrict__ bias1,
                                                 void* __restrict__ Cv,
                                                 int M, int N, int K, int klen) {
  constexpr int NI = BN / 32;
  constexpr int BCH = BN / 32;
  __shared__ __align__(16) unsigned short lA[2][128 * 64];
  __shared__ __align__(16) unsigned short lB[2][BN * 64];
  int tid = threadIdx.x, wave = tid >> 6, lane = tid & 63;
  int wm = wave & 1, wn = wave >> 1;
  int gx = gridDim.x;
  int nxy = gx * gridDim.y;
  int lin = blockIdx.x + gx * blockIdx.y;
  int nch = nxy >> 3;
  int nl = (lin & 7) * nch + (lin >> 3);
  int bx = nl % gx, by = nl / gx;
  int bm = by * 128, bn = bx * BN;
  int kbase = blockIdx.z * klen;
  int srow = lane >> 3;
  int sg = (lane & 7) ^ srow;
  const unsigned short* ag[4];
  const unsigned short* bg[BCH];
  #pragma unroll
  for (int p = 0; p < 4; ++p) {
    int row = (wave * 4 + p) * 8 + srow;
    ag[p] = A + (size_t)(bm + row) * K + kbase + sg * 8;
  }
  #pragma unroll
  for (int p = 0; p < BCH; ++p) {
    int row = (wave * BCH + p) * 8 + srow;
    bg[p] = B + (size_t)(bn + row) * K + kbase + sg * 8;
  }
  auto stage = [&](int buf) {
    #pragma unroll
    for (int p = 0; p < 4; ++p) { gload16(ag[p], &lA[buf][(wave * 4 + p) * 512]); ag[p] += 64; }
    #pragma unroll
    for (int p = 0; p < BCH; ++p) { gload16(bg[p], &lB[buf][(wave * BCH + p) * 512]); bg[p] += 64; }
  };
  f32x4 acc[4][NI] = {};
  int nt = klen / 64;
  stage(0);
  __syncthreads();
  int cur = 0;
  int lrow = lane & 15, glq = lane >> 4;
  for (int t = 0; t < nt; ++t) {
    if (t + 1 < nt) stage(cur ^ 1);
    short8 bf[2][NI];
    #pragma unroll
    for (int kk = 0; kk < 2; ++kk)
      #pragma unroll
      for (int ni = 0; ni < NI; ++ni) {
        int row = wn * (BN / 2) + ni * 16 + lrow;
        int pg = (kk * 4 + glq) ^ (row & 7);
        bf[kk][ni] = *(const short8*)&lB[cur][row * 64 + pg * 8];
      }
    #pragma unroll
    for (int mi = 0; mi < 4; ++mi)
      #pragma unroll
      for (int kk = 0; kk < 2; ++kk) {
        int row = wm * 64 + mi * 16 + lrow;
        int pg = (kk * 4 + glq) ^ (row & 7);
        short8 af = *(const short8*)&lA[cur][row * 64 + pg * 8];
        #pragma unroll
        for (int ni = 0; ni < NI; ++ni)
          acc[mi][ni] = __builtin_amdgcn_mfma_f32_16x16x32_bf16(af, bf[kk][ni], acc[mi][ni], 0, 0, 0);
      }
    __syncthreads();
    cur ^= 1;
  }
  #pragma unroll
  for (int mi = 0; mi < 4; ++mi)
    #pragma unroll
    for (int ni = 0; ni < NI; ++ni) {
      int col = bn + wn * (BN / 2) + ni * 16 + lrow;
      float bv = 0.f;
      if (BIAS) bv = (col < 512) ? bias0[col] : bias1[col - 512];
      #pragma unroll
      for (int j = 0; j < 4; ++j) {
        int row = bm + wm * 64 + mi * 16 + glq * 4 + j;
        float vv = acc[mi][ni][j] + bv;
        if (CBF16) {
          unsigned short* C = (unsigned short*)Cv + (size_t)blockIdx.z * M * N;
          C[(size_t)row * N + col] = f2bf(vv);
        } else {
          float* C = (float*)Cv + (size_t)blockIdx.z * M * N;
          C[(size_t)row * N + col] = vv;
        }
      }
    }
}

// ---------------- per-pair exp(score): R9 form — 1 pair/wave, TLP-driven, early exit ----------------
// R12 post-mortem: 8-pair reg batching re-serialized (VGPR=52 < needed) and halved
// occupancy. R9's 1-pair/wave at 32768 blocks rode TLP to ~3 TB/s. Validity check
// (one wave-uniform 4B load) retires ~50% of waves before the 2KB Q/K gather.
__global__ __launch_bounds__(256) void k_scores(const unsigned short* __restrict__ QKb,
                                                const int* __restrict__ pairs,
                                                const float* __restrict__ agg,
                                                float* __restrict__ es,
                                                float* __restrict__ sumexp,
                                                int* __restrict__ scnt) {
  int wave = threadIdx.x >> 6, lane = threadIdx.x & 63;
  int e = blockIdx.x * 4 + wave;
  int2 pr = *(const int2*)&pairs[2 * e];
  int sub = pr.x, obj = pr.y;
  bool valid = (sub != obj) && (agg[(size_t)sub * N_INST + obj] != 0.f);
  if (!valid) {
    if (lane == 0) es[(size_t)e * 8] = -1.f;
    return;
  }
  short8 q8 = *(const short8*)&QKb[(size_t)sub * 1024 + lane * 8];
  short8 k8 = *(const short8*)&QKb[(size_t)obj * 1024 + 512 + lane * 8];
  float p = 0.f;
  #pragma unroll
  for (int j = 0; j < 8; ++j)
    p += bf2f((unsigned short)q8[j]) * bf2f((unsigned short)k8[j]);
  p += __shfl_xor(p, 1);
  p += __shfl_xor(p, 2);
  p += __shfl_xor(p, 4);
  float ev = expf(p * 0.125f);   // / sqrt(64)
  int h = lane >> 3;
  if ((lane & 7) == 0) {
    es[(size_t)e * 8 + h] = ev;
    atomicAdd(&sumexp[sub * 8 + h], ev);
  }
  if (lane == 0) atomicAdd(&scnt[sub], 1);
}

// ---------------- per-row denominators -> invden, base ----------------
__global__ __launch_bounds__(256) void k_denom(const float* __restrict__ sumexp,
                                               const int* __restrict__ scnt,
                                               const int* __restrict__ acnt,
                                               float* __restrict__ invden,
                                               float* __restrict__ base) {
  int i = blockIdx.x * 256 + threadIdx.x;
  if (i >= N_INST) return;
  float c0 = (float)(acnt[i] - scnt[i]);
  const float E0 = expf(1e-7f);
  float bsum = 0.f;
  #pragma unroll
  for (int h = 0; h < NHEAD; ++h) {
    float inv = 1.0f / (E0 + c0 + sumexp[i * NHEAD + h]);
    invden[i * NHEAD + h] = inv;
    bsum += inv;
  }
  base[i] = bsum * (1.0f / NHEAD);
}

// ---------------- scatter ratio entries into mask ----------------
__global__ __launch_bounds__(256) void k_scatter(const int* __restrict__ pairs,
                                                 const float* __restrict__ es,
                                                 const float* __restrict__ invden,
                                                 const float* __restrict__ base,
                                                 unsigned short* __restrict__ maskb) {
  int e = blockIdx.x * 256 + threadIdx.x;
  if (e >= NPAIR) return;
  float4 e0 = *(const float4*)&es[(size_t)e * 8];
  if (e0.x < 0.f) return;
  float4 e1 = *(const float4*)&es[(size_t)e * 8 + 4];
  int sub = pairs[2 * e], obj = pairs[2 * e + 1];
  const float* inv = &invden[sub * 8];
  float f = e0.x * inv[0] + e0.y * inv[1] + e0.z * inv[2] + e0.w * inv[3] +
            e1.x * inv[4] + e1.y * inv[5] + e1.z * inv[6] + e1.w * inv[7];
  maskb[(size_t)sub * N_INST + obj] = f2bf(f * 0.125f / base[sub]);
}

// ---------------- reduce split-K=4 bf16 partials + row scale ----------------
__global__ __launch_bounds__(256) void k_redscale(const unsigned short* __restrict__ P,
                                                  const float* __restrict__ base,
                                                  float* __restrict__ out) {
  size_t idx = ((size_t)blockIdx.x * 256 + threadIdx.x) * 4;
  int i = (int)(idx >> 9);
  const size_t S = (size_t)N_INST * 512;
  u16x4 a = *(const u16x4*)&P[idx];
  u16x4 b = *(const u16x4*)&P[idx + S];
  u16x4 c = *(const u16x4*)&P[idx + 2 * S];
  u16x4 d = *(const u16x4*)&P[idx + 3 * S];
  float s = base[i];
  float4 o;
  o.x = s * (bf2f(a[0]) + bf2f(b[0]) + bf2f(c[0]) + bf2f(d[0]));
  o.y = s * (bf2f(a[1]) + bf2f(b[1]) + bf2f(c[1]) + bf2f(d[1]));
  o.z = s * (bf2f(a[2]) + bf2f(b[2]) + bf2f(c[2]) + bf2f(d[2]));
  o.w = s * (bf2f(a[3]) + bf2f(b[3]) + bf2f(c[3]) + bf2f(d[3]));
  *(float4*)&out[idx] = o;
}

extern "C" void kernel_launch(void* const* d_in, const int* in_sizes, int n_in,
                              void* d_out, int out_size, void* d_ws, size_t ws_size,
                              hipStream_t stream) {
  const float* x   = (const float*)d_in[0];
  const float* agg = (const float*)d_in[1];
  const int*   prs = (const int*)d_in[2];
  const float* w_q = (const float*)d_in[3];
  const float* b_q = (const float*)d_in[4];
  const float* w_k = (const float*)d_in[5];
  const float* b_k = (const float*)d_in[6];
  float* out = (float*)d_out;

  char* ws = (char*)d_ws;
  size_t off = 0;
  auto alloc = [&](size_t bytes) -> void* {
    void* p = ws + off;
    off += (bytes + 255) & ~(size_t)255;
    return p;
  };
  unsigned short* xb    = (unsigned short*)alloc((size_t)N_INST * D_FEAT * 2);
  unsigned short* xbT   = (unsigned short*)alloc((size_t)D_FEAT * N_INST * 2);
  unsigned short* wqkb  = (unsigned short*)alloc((size_t)1024 * D_FEAT * 2);
  void*           QKP   = alloc((size_t)N_INST * 512 * 2 * 4);  // 8MB QK bf16 table; reused as 4x bf16 partials (16MB)
  float*          es    = (float*)alloc((size_t)NPAIR * NHEAD * 4);
  float*          sumexp= (float*)alloc((size_t)N_INST * NHEAD * 4);
  int*            scnt  = (int*)alloc((size_t)N_INST * 4);
  int*            acnt  = (int*)alloc((size_t)N_INST * 4);
  float*          invden= (float*)alloc((size_t)N_INST * NHEAD * 4);
  float*          base  = (float*)alloc((size_t)N_INST * 4);
  unsigned short* maskb = (unsigned short*)alloc((size_t)N_INST * N_INST * 2);

  hipMemsetAsync(sumexp, 0, (size_t)N_INST * NHEAD * 4, stream);
  hipMemsetAsync(scnt, 0, (size_t)N_INST * 4, stream);

  k_castw<<<dim3(D_FEAT * D_FEAT / 4 / 256, 2), 256, 0, stream>>>(w_q, w_k, wqkb);
  k_xprep<<<dim3(D_FEAT / 32, N_INST / 32), 256, 0, stream>>>(x, xb, xbT);
  k_mask_acnt<<<dim3(N_INST), 256, 0, stream>>>(agg, maskb, acnt);

  // fused Q|K projection: C (4096x1024 bf16) = xb (4096x512) * wqkb (1024x512)^T + bias
  k_gemm<1, 1, 64><<<dim3(1024 / 64, N_INST / 128, 1), 256, 0, stream>>>(
      xb, wqkb, b_q, b_k, QKP, N_INST, 1024, D_FEAT, D_FEAT);

  k_scores<<<dim3(NPAIR / 4), 256, 0, stream>>>((const unsigned short*)QKP, prs, agg, es, sumexp, scnt);
  k_denom<<<dim3(N_INST / 256), 256, 0, stream>>>(sumexp, scnt, acnt, invden, base);
  k_scatter<<<dim3(NPAIR / 256), 256, 0, stream>>>(prs, es, invden, base, maskb);

  // bf16 partials = maskb (4096x4096) * xbT (512x4096)^T, 128x128 tile, split-K=4
  k_gemm<0, 1, 128><<<dim3(512 / 128, N_INST / 128, 4), 256, 0, stream>>>(
      maskb, xbT, nullptr, nullptr, QKP, N_INST, 512, N_INST, N_INST / 4);

  k_redscale<<<dim3(N_INST * 512 / 4 / 256), 256, 0, stream>>>((const unsigned short*)QKP, base, out);
}

// Round 14
// 113.393 us; speedup vs baseline: 1.5242x; 1.0380x over previous
//
#include <hip/hip_runtime.h>

#define N_INST 4096
#define D_FEAT 512
#define NHEAD 8
#define NPAIR 131072

typedef __attribute__((ext_vector_type(8))) short short8;
typedef __attribute__((ext_vector_type(4))) float f32x4;
typedef __attribute__((ext_vector_type(4))) unsigned short u16x4;

__device__ inline unsigned short f2bf(float f) {
  union { float f; unsigned u; } v; v.f = f;
  unsigned r = v.u + 0x7fffu + ((v.u >> 16) & 1u);
  return (unsigned short)(r >> 16);
}
__device__ inline float bf2f(unsigned short b) {
  union { unsigned u; float f; } v; v.u = ((unsigned)b) << 16; return v.f;
}
__device__ inline void gload16(const void* g, void* l) {
  __builtin_amdgcn_global_load_lds((const __attribute__((address_space(1))) unsigned int*)g,
                                   (__attribute__((address_space(3))) unsigned int*)l, 16, 0, 0);
}

// ---------------- both weight casts in one launch (y=0 -> w_q, y=1 -> w_k) ----------------
__global__ __launch_bounds__(256) void k_castw(const float* __restrict__ wq,
                                               const float* __restrict__ wk,
                                               unsigned short* __restrict__ dst) {
  const float* src = blockIdx.y ? wk : wq;
  unsigned short* d = dst + (size_t)blockIdx.y * D_FEAT * D_FEAT;
  int i = (blockIdx.x * 256 + threadIdx.x) * 4;
  float4 v = *(const float4*)&src[i];
  ushort4 o;
  o.x = f2bf(v.x); o.y = f2bf(v.y); o.z = f2bf(v.z); o.w = f2bf(v.w);
  *(ushort4*)&d[i] = o;
}

// ---------------- x (4096x512 f32) -> xb bf16 AND xT bf16 (512x4096), one read ----------------
__global__ __launch_bounds__(256) void k_xprep(const float* __restrict__ x,
                                               unsigned short* __restrict__ xb,
                                               unsigned short* __restrict__ xT) {
  __shared__ float t[32][33];
  int bx = blockIdx.x, by = blockIdx.y;
  int tx = threadIdx.x & 31, ty = threadIdx.x >> 5;
  #pragma unroll
  for (int r = 0; r < 4; ++r) {
    int row = by * 32 + ty + r * 8;
    float v = x[(size_t)row * D_FEAT + bx * 32 + tx];
    t[ty + r * 8][tx] = v;
    xb[(size_t)row * D_FEAT + bx * 32 + tx] = f2bf(v);
  }
  __syncthreads();
  #pragma unroll
  for (int r = 0; r < 4; ++r)
    xT[(size_t)(bx * 32 + ty + r * 8) * N_INST + by * 32 + tx] = f2bf(t[tx][ty + r * 8]);
}

// ---------------- block-per-row: bf16 mask (diag=1) + off-diag count + nibble validity ----------------
// Extra output: vbits (4MB) — byte b packs validity bits for 4 consecutive columns.
// k_scores' random 4B probes over the 64MB agg become byte probes over a 4MB
// L3/L2-resident table (R13 theory: validity fills were ~16MB of k_scores' FETCH).
__global__ __launch_bounds__(256) void k_mask_acnt(const float* __restrict__ agg,
                                                   unsigned short* __restrict__ maskb,
                                                   int* __restrict__ acnt,
                                                   unsigned char* __restrict__ vbits) {
  int i = blockIdx.x;
  const f32x4* row = (const f32x4*)(agg + (size_t)i * N_INST);
  u16x4* mrow = (u16x4*)(maskb + (size_t)i * N_INST);
  unsigned char* vrow = vbits + (size_t)i * (N_INST / 4);
  int tid = threadIdx.x;
  f32x4 v[4];
  #pragma unroll
  for (int u = 0; u < 4; ++u)
    v[u] = __builtin_nontemporal_load(&row[u * 256 + tid]);
  int cnt = 0;
  #pragma unroll
  for (int u = 0; u < 4; ++u) {
    int t = u * 256 + tid;
    int b0 = (v[u][0] != 0.f), b1 = (v[u][1] != 0.f), b2 = (v[u][2] != 0.f), b3 = (v[u][3] != 0.f);
    u16x4 m;
    m[0] = b0 ? 0x3F80 : 0;
    m[1] = b1 ? 0x3F80 : 0;
    m[2] = b2 ? 0x3F80 : 0;
    m[3] = b3 ? 0x3F80 : 0;
    cnt += b0 + b1 + b2 + b3;
    vrow[t] = (unsigned char)(b0 | (b1 << 1) | (b2 << 2) | (b3 << 3));
    int j = t * 4;
    if (i >= j && i < j + 4) {
      int d = i - j;
      m[d] = 0x3F80;                    // diagonal always present
      cnt -= (v[u][d] != 0.f);          // diag not counted as generic
    }
    __builtin_nontemporal_store(m, &mrow[t]);
  }
  #pragma unroll
  for (int msk = 1; msk < 64; msk <<= 1) cnt += __shfl_xor(cnt, msk);
  __shared__ int wsum[4];
  if ((threadIdx.x & 63) == 0) wsum[threadIdx.x >> 6] = cnt;
  __syncthreads();
  if (threadIdx.x == 0) acnt[i] = wsum[0] + wsum[1] + wsum[2] + wsum[3];
}

// ---------------- NT bf16 MFMA GEMM, BM=128, BN templated (64 or 128), BK=64 ----------------
template<int BIAS, int CBF16, int BN>
__global__ __launch_bounds__(256, 2) void k_gemm(const unsigned short* __restrict__ A,
                                                 const unsigned short* __restrict__ B,
                                                 const float* __restrict__ bias0,
                                                 const float* __restrict__ bias1,
                                                 void* __restrict__ Cv,
                                                 int M, int N, int K, int klen) {
  constexpr int NI = BN / 32;
  constexpr int BCH = BN / 32;
  __shared__ __align__(16) unsigned short lA[2][128 * 64];
  __shared__ __align__(16) unsigned short lB[2][BN * 64];
  int tid = threadIdx.x, wave = tid >> 6, lane = tid & 63;
  int wm = wave & 1, wn = wave >> 1;
  int gx = gridDim.x;
  int nxy = gx * gridDim.y;
  int lin = blockIdx.x + gx * blockIdx.y;
  int nch = nxy >> 3;
  int nl = (lin & 7) * nch + (lin >> 3);
  int bx = nl % gx, by = nl / gx;
  int bm = by * 128, bn = bx * BN;
  int kbase = blockIdx.z * klen;
  int srow = lane >> 3;
  int sg = (lane & 7) ^ srow;
  const unsigned short* ag[4];
  const unsigned short* bg[BCH];
  #pragma unroll
  for (int p = 0; p < 4; ++p) {
    int row = (wave * 4 + p) * 8 + srow;
    ag[p] = A + (size_t)(bm + row) * K + kbase + sg * 8;
  }
  #pragma unroll
  for (int p = 0; p < BCH; ++p) {
    int row = (wave * BCH + p) * 8 + srow;
    bg[p] = B + (size_t)(bn + row) * K + kbase + sg * 8;
  }
  auto stage = [&](int buf) {
    #pragma unroll
    for (int p = 0; p < 4; ++p) { gload16(ag[p], &lA[buf][(wave * 4 + p) * 512]); ag[p] += 64; }
    #pragma unroll
    for (int p = 0; p < BCH; ++p) { gload16(bg[p], &lB[buf][(wave * BCH + p) * 512]); bg[p] += 64; }
  };
  f32x4 acc[4][NI] = {};
  int nt = klen / 64;
  stage(0);
  __syncthreads();
  int cur = 0;
  int lrow = lane & 15, glq = lane >> 4;
  for (int t = 0; t < nt; ++t) {
    if (t + 1 < nt) stage(cur ^ 1);
    short8 bf[2][NI];
    #pragma unroll
    for (int kk = 0; kk < 2; ++kk)
      #pragma unroll
      for (int ni = 0; ni < NI; ++ni) {
        int row = wn * (BN / 2) + ni * 16 + lrow;
        int pg = (kk * 4 + glq) ^ (row & 7);
        bf[kk][ni] = *(const short8*)&lB[cur][row * 64 + pg * 8];
      }
    #pragma unroll
    for (int mi = 0; mi < 4; ++mi)
      #pragma unroll
      for (int kk = 0; kk < 2; ++kk) {
        int row = wm * 64 + mi * 16 + lrow;
        int pg = (kk * 4 + glq) ^ (row & 7);
        short8 af = *(const short8*)&lA[cur][row * 64 + pg * 8];
        #pragma unroll
        for (int ni = 0; ni < NI; ++ni)
          acc[mi][ni] = __builtin_amdgcn_mfma_f32_16x16x32_bf16(af, bf[kk][ni], acc[mi][ni], 0, 0, 0);
      }
    __syncthreads();
    cur ^= 1;
  }
  #pragma unroll
  for (int mi = 0; mi < 4; ++mi)
    #pragma unroll
    for (int ni = 0; ni < NI; ++ni) {
      int col = bn + wn * (BN / 2) + ni * 16 + lrow;
      float bv = 0.f;
      if (BIAS) bv = (col < 512) ? bias0[col] : bias1[col - 512];
      #pragma unroll
      for (int j = 0; j < 4; ++j) {
        int row = bm + wm * 64 + mi * 16 + glq * 4 + j;
        float vv = acc[mi][ni][j] + bv;
        if (CBF16) {
          unsigned short* C = (unsigned short*)Cv + (size_t)blockIdx.z * M * N;
          C[(size_t)row * N + col] = f2bf(vv);
        } else {
          float* C = (float*)Cv + (size_t)blockIdx.z * M * N;
          C[(size_t)row * N + col] = vv;
        }
      }
    }
}

// ---------------- per-pair exp(score): 1 pair/wave, nibble-table validity, early exit ----------------
__global__ __launch_bounds__(256) void k_scores(const unsigned short* __restrict__ QKb,
                                                const int* __restrict__ pairs,
                                                const unsigned char* __restrict__ vbits,
                                                float* __restrict__ es,
                                                float* __restrict__ sumexp,
                                                int* __restrict__ scnt) {
  int wave = threadIdx.x >> 6, lane = threadIdx.x & 63;
  int e = blockIdx.x * 4 + wave;
  int2 pr = *(const int2*)&pairs[2 * e];
  int sub = pr.x, obj = pr.y;
  unsigned char nb = vbits[(size_t)sub * (N_INST / 4) + (obj >> 2)];
  bool valid = (sub != obj) && ((nb >> (obj & 3)) & 1);
  if (!valid) {
    if (lane == 0) es[(size_t)e * 8] = -1.f;
    return;
  }
  short8 q8 = *(const short8*)&QKb[(size_t)sub * 1024 + lane * 8];
  short8 k8 = *(const short8*)&QKb[(size_t)obj * 1024 + 512 + lane * 8];
  float p = 0.f;
  #pragma unroll
  for (int j = 0; j < 8; ++j)
    p += bf2f((unsigned short)q8[j]) * bf2f((unsigned short)k8[j]);
  p += __shfl_xor(p, 1);
  p += __shfl_xor(p, 2);
  p += __shfl_xor(p, 4);
  float ev = expf(p * 0.125f);   // / sqrt(64)
  int h = lane >> 3;
  if ((lane & 7) == 0) {
    es[(size_t)e * 8 + h] = ev;
    atomicAdd(&sumexp[sub * 8 + h], ev);
  }
  if (lane == 0) atomicAdd(&scnt[sub], 1);
}

// ---------------- per-row denominators -> invden, base ----------------
__global__ __launch_bounds__(256) void k_denom(const float* __restrict__ sumexp,
                                               const int* __restrict__ scnt,
                                               const int* __restrict__ acnt,
                                               float* __restrict__ invden,
                                               float* __restrict__ base) {
  int i = blockIdx.x * 256 + threadIdx.x;
  if (i >= N_INST) return;
  float c0 = (float)(acnt[i] - scnt[i]);
  const float E0 = expf(1e-7f);
  float bsum = 0.f;
  #pragma unroll
  for (int h = 0; h < NHEAD; ++h) {
    float inv = 1.0f / (E0 + c0 + sumexp[i * NHEAD + h]);
    invden[i * NHEAD + h] = inv;
    bsum += inv;
  }
  base[i] = bsum * (1.0f / NHEAD);
}

// ---------------- scatter ratio entries into mask ----------------
__global__ __launch_bounds__(256) void k_scatter(const int* __restrict__ pairs,
                                                 const float* __restrict__ es,
                                                 const float* __restrict__ invden,
                                                 const float* __restrict__ base,
                                                 unsigned short* __restrict__ maskb) {
  int e = blockIdx.x * 256 + threadIdx.x;
  if (e >= NPAIR) return;
  float4 e0 = *(const float4*)&es[(size_t)e * 8];
  if (e0.x < 0.f) return;
  float4 e1 = *(const float4*)&es[(size_t)e * 8 + 4];
  int sub = pairs[2 * e], obj = pairs[2 * e + 1];
  const float* inv = &invden[sub * 8];
  float f = e0.x * inv[0] + e0.y * inv[1] + e0.z * inv[2] + e0.w * inv[3] +
            e1.x * inv[4] + e1.y * inv[5] + e1.z * inv[6] + e1.w * inv[7];
  maskb[(size_t)sub * N_INST + obj] = f2bf(f * 0.125f / base[sub]);
}

// ---------------- reduce split-K=4 bf16 partials + row scale ----------------
__global__ __launch_bounds__(256) void k_redscale(const unsigned short* __restrict__ P,
                                                  const float* __restrict__ base,
                                                  float* __restrict__ out) {
  size_t idx = ((size_t)blockIdx.x * 256 + threadIdx.x) * 4;
  int i = (int)(idx >> 9);
  const size_t S = (size_t)N_INST * 512;
  u16x4 a = *(const u16x4*)&P[idx];
  u16x4 b = *(const u16x4*)&P[idx + S];
  u16x4 c = *(const u16x4*)&P[idx + 2 * S];
  u16x4 d = *(const u16x4*)&P[idx + 3 * S];
  float s = base[i];
  float4 o;
  o.x = s * (bf2f(a[0]) + bf2f(b[0]) + bf2f(c[0]) + bf2f(d[0]));
  o.y = s * (bf2f(a[1]) + bf2f(b[1]) + bf2f(c[1]) + bf2f(d[1]));
  o.z = s * (bf2f(a[2]) + bf2f(b[2]) + bf2f(c[2]) + bf2f(d[2]));
  o.w = s * (bf2f(a[3]) + bf2f(b[3]) + bf2f(c[3]) + bf2f(d[3]));
  *(float4*)&out[idx] = o;
}

extern "C" void kernel_launch(void* const* d_in, const int* in_sizes, int n_in,
                              void* d_out, int out_size, void* d_ws, size_t ws_size,
                              hipStream_t stream) {
  const float* x   = (const float*)d_in[0];
  const float* agg = (const float*)d_in[1];
  const int*   prs = (const int*)d_in[2];
  const float* w_q = (const float*)d_in[3];
  const float* b_q = (const float*)d_in[4];
  const float* w_k = (const float*)d_in[5];
  const float* b_k = (const float*)d_in[6];
  float* out = (float*)d_out;

  char* ws = (char*)d_ws;
  size_t off = 0;
  auto alloc = [&](size_t bytes) -> void* {
    void* p = ws + off;
    off += (bytes + 255) & ~(size_t)255;
    return p;
  };
  unsigned short* xb    = (unsigned short*)alloc((size_t)N_INST * D_FEAT * 2);
  unsigned short* xbT   = (unsigned short*)alloc((size_t)D_FEAT * N_INST * 2);
  unsigned short* wqkb  = (unsigned short*)alloc((size_t)1024 * D_FEAT * 2);
  void*           QKP   = alloc((size_t)N_INST * 512 * 2 * 4);  // 8MB QK bf16 table; reused as 4x bf16 partials (16MB)
  float*          es    = (float*)alloc((size_t)NPAIR * NHEAD * 4);
  float*          sumexp= (float*)alloc((size_t)N_INST * NHEAD * 4);
  int*            scnt  = (int*)alloc((size_t)N_INST * 4);
  int*            acnt  = (int*)alloc((size_t)N_INST * 4);
  float*          invden= (float*)alloc((size_t)N_INST * NHEAD * 4);
  float*          base  = (float*)alloc((size_t)N_INST * 4);
  unsigned char*  vbits = (unsigned char*)alloc((size_t)N_INST * (N_INST / 4));
  unsigned short* maskb = (unsigned short*)alloc((size_t)N_INST * N_INST * 2);

  hipMemsetAsync(sumexp, 0, (size_t)N_INST * NHEAD * 4, stream);
  hipMemsetAsync(scnt, 0, (size_t)N_INST * 4, stream);

  k_castw<<<dim3(D_FEAT * D_FEAT / 4 / 256, 2), 256, 0, stream>>>(w_q, w_k, wqkb);
  k_xprep<<<dim3(D_FEAT / 32, N_INST / 32), 256, 0, stream>>>(x, xb, xbT);
  k_mask_acnt<<<dim3(N_INST), 256, 0, stream>>>(agg, maskb, acnt, vbits);

  // fused Q|K projection: C (4096x1024 bf16) = xb (4096x512) * wqkb (1024x512)^T + bias
  k_gemm<1, 1, 64><<<dim3(1024 / 64, N_INST / 128, 1), 256, 0, stream>>>(
      xb, wqkb, b_q, b_k, QKP, N_INST, 1024, D_FEAT, D_FEAT);

  k_scores<<<dim3(NPAIR / 4), 256, 0, stream>>>((const unsigned short*)QKP, prs, vbits, es, sumexp, scnt);
  k_denom<<<dim3(N_INST / 256), 256, 0, stream>>>(sumexp, scnt, acnt, invden, base);
  k_scatter<<<dim3(NPAIR / 256), 256, 0, stream>>>(prs, es, invden, base, maskb);

  // bf16 partials = maskb (4096x4096) * xbT (512x4096)^T, 128x128 tile, split-K=4
  k_gemm<0, 1, 128><<<dim3(512 / 128, N_INST / 128, 4), 256, 0, stream>>>(
      maskb, xbT, nullptr, nullptr, QKP, N_INST, 512, N_INST, N_INST / 4);

  k_redscale<<<dim3(N_INST * 512 / 4 / 256), 256, 0, stream>>>((const unsigned short*)QKP, base, out);
}

// Round 15
// 107.458 us; speedup vs baseline: 1.6084x; 1.0552x over previous
//
#include <hip/hip_runtime.h>

#define N_INST 4096
#define D_FEAT 512
#define NHEAD 8
#define NPAIR 131072

typedef __attribute__((ext_vector_type(8))) short short8;
typedef __attribute__((ext_vector_type(4))) float f32x4;
typedef __attribute__((ext_vector_type(4))) unsigned short u16x4;

__device__ inline unsigned short f2bf(float f) {
  union { float f; unsigned u; } v; v.f = f;
  unsigned r = v.u + 0x7fffu + ((v.u >> 16) & 1u);
  return (unsigned short)(r >> 16);
}
__device__ inline float bf2f(unsigned short b) {
  union { unsigned u; float f; } v; v.u = ((unsigned)b) << 16; return v.f;
}
__device__ inline void gload16(const void* g, void* l) {
  __builtin_amdgcn_global_load_lds((const __attribute__((address_space(1))) unsigned int*)g,
                                   (__attribute__((address_space(3))) unsigned int*)l, 16, 0, 0);
}

// ---------------- both weight casts in one launch (y=0 -> w_q, y=1 -> w_k) ----------------
__global__ __launch_bounds__(256) void k_castw(const float* __restrict__ wq,
                                               const float* __restrict__ wk,
                                               unsigned short* __restrict__ dst) {
  const float* src = blockIdx.y ? wk : wq;
  unsigned short* d = dst + (size_t)blockIdx.y * D_FEAT * D_FEAT;
  int i = (blockIdx.x * 256 + threadIdx.x) * 4;
  float4 v = *(const float4*)&src[i];
  ushort4 o;
  o.x = f2bf(v.x); o.y = f2bf(v.y); o.z = f2bf(v.z); o.w = f2bf(v.w);
  *(ushort4*)&d[i] = o;
}

// ---------------- x (4096x512 f32) -> xb bf16 AND xT bf16 (512x4096), one read ----------------
__global__ __launch_bounds__(256) void k_xprep(const float* __restrict__ x,
                                               unsigned short* __restrict__ xb,
                                               unsigned short* __restrict__ xT) {
  __shared__ float t[32][33];
  int bx = blockIdx.x, by = blockIdx.y;
  int tx = threadIdx.x & 31, ty = threadIdx.x >> 5;
  #pragma unroll
  for (int r = 0; r < 4; ++r) {
    int row = by * 32 + ty + r * 8;
    float v = x[(size_t)row * D_FEAT + bx * 32 + tx];
    t[ty + r * 8][tx] = v;
    xb[(size_t)row * D_FEAT + bx * 32 + tx] = f2bf(v);
  }
  __syncthreads();
  #pragma unroll
  for (int r = 0; r < 4; ++r)
    xT[(size_t)(bx * 32 + ty + r * 8) * N_INST + by * 32 + tx] = f2bf(t[tx][ty + r * 8]);
}

// ---------------- 2 rows/block: bf16 mask (diag=1) + off-diag count + nibble validity ----------------
// 8 NT loads in flight per thread (row has only 4 chunks/thread -> pair rows to
// double MLP; R14 at 4-deep was ~4.3 TB/s on a ~5.5 TB/s mixed-stream ceiling).
__global__ __launch_bounds__(256) void k_mask_acnt(const float* __restrict__ agg,
                                                   unsigned short* __restrict__ maskb,
                                                   int* __restrict__ acnt,
                                                   unsigned char* __restrict__ vbits) {
  int i0 = blockIdx.x * 2;
  const f32x4* r0 = (const f32x4*)(agg + (size_t)i0 * N_INST);
  const f32x4* r1 = (const f32x4*)(agg + (size_t)(i0 + 1) * N_INST);
  u16x4* m0 = (u16x4*)(maskb + (size_t)i0 * N_INST);
  u16x4* m1 = (u16x4*)(maskb + (size_t)(i0 + 1) * N_INST);
  unsigned char* v0r = vbits + (size_t)i0 * (N_INST / 4);
  unsigned char* v1r = vbits + (size_t)(i0 + 1) * (N_INST / 4);
  int tid = threadIdx.x;
  f32x4 v[8];
  #pragma unroll
  for (int u = 0; u < 4; ++u) {
    v[u]     = __builtin_nontemporal_load(&r0[u * 256 + tid]);
    v[4 + u] = __builtin_nontemporal_load(&r1[u * 256 + tid]);
  }
  int cnt0 = 0, cnt1 = 0;
  #pragma unroll
  for (int u = 0; u < 4; ++u) {
    int t = u * 256 + tid;
    int j = t * 4;
    // row i0
    {
      f32x4 w = v[u];
      int b0 = (w[0] != 0.f), b1 = (w[1] != 0.f), b2 = (w[2] != 0.f), b3 = (w[3] != 0.f);
      u16x4 m;
      m[0] = b0 ? 0x3F80 : 0; m[1] = b1 ? 0x3F80 : 0;
      m[2] = b2 ? 0x3F80 : 0; m[3] = b3 ? 0x3F80 : 0;
      cnt0 += b0 + b1 + b2 + b3;
      v0r[t] = (unsigned char)(b0 | (b1 << 1) | (b2 << 2) | (b3 << 3));
      if (i0 >= j && i0 < j + 4) {
        int d = i0 - j;
        m[d] = 0x3F80;
        cnt0 -= (w[d] != 0.f);
      }
      __builtin_nontemporal_store(m, &m0[t]);
    }
    // row i0+1
    {
      f32x4 w = v[4 + u];
      int i1 = i0 + 1;
      int b0 = (w[0] != 0.f), b1 = (w[1] != 0.f), b2 = (w[2] != 0.f), b3 = (w[3] != 0.f);
      u16x4 m;
      m[0] = b0 ? 0x3F80 : 0; m[1] = b1 ? 0x3F80 : 0;
      m[2] = b2 ? 0x3F80 : 0; m[3] = b3 ? 0x3F80 : 0;
      cnt1 += b0 + b1 + b2 + b3;
      v1r[t] = (unsigned char)(b0 | (b1 << 1) | (b2 << 2) | (b3 << 3));
      if (i1 >= j && i1 < j + 4) {
        int d = i1 - j;
        m[d] = 0x3F80;
        cnt1 -= (w[d] != 0.f);
      }
      __builtin_nontemporal_store(m, &m1[t]);
    }
  }
  #pragma unroll
  for (int msk = 1; msk < 64; msk <<= 1) {
    cnt0 += __shfl_xor(cnt0, msk);
    cnt1 += __shfl_xor(cnt1, msk);
  }
  __shared__ int wsum[4][2];
  if ((threadIdx.x & 63) == 0) {
    wsum[threadIdx.x >> 6][0] = cnt0;
    wsum[threadIdx.x >> 6][1] = cnt1;
  }
  __syncthreads();
  if (threadIdx.x == 0)
    acnt[i0] = wsum[0][0] + wsum[1][0] + wsum[2][0] + wsum[3][0];
  if (threadIdx.x == 1)
    acnt[i0 + 1] = wsum[0][1] + wsum[1][1] + wsum[2][1] + wsum[3][1];
}

// ---------------- NT bf16 MFMA GEMM, BM=128, BN templated (64 or 128), BK=64 ----------------
template<int BIAS, int CBF16, int BN>
__global__ __launch_bounds__(256, 2) void k_gemm(const unsigned short* __restrict__ A,
                                                 const unsigned short* __restrict__ B,
                                                 const float* __restrict__ bias0,
                                                 const float* __restrict__ bias1,
                                                 void* __restrict__ Cv,
                                                 int M, int N, int K, int klen) {
  constexpr int NI = BN / 32;
  constexpr int BCH = BN / 32;
  __shared__ __align__(16) unsigned short lA[2][128 * 64];
  __shared__ __align__(16) unsigned short lB[2][BN * 64];
  int tid = threadIdx.x, wave = tid >> 6, lane = tid & 63;
  int wm = wave & 1, wn = wave >> 1;
  int gx = gridDim.x;
  int nxy = gx * gridDim.y;
  int lin = blockIdx.x + gx * blockIdx.y;
  int nch = nxy >> 3;
  int nl = (lin & 7) * nch + (lin >> 3);
  int bx = nl % gx, by = nl / gx;
  int bm = by * 128, bn = bx * BN;
  int kbase = blockIdx.z * klen;
  int srow = lane >> 3;
  int sg = (lane & 7) ^ srow;
  const unsigned short* ag[4];
  const unsigned short* bg[BCH];
  #pragma unroll
  for (int p = 0; p < 4; ++p) {
    int row = (wave * 4 + p) * 8 + srow;
    ag[p] = A + (size_t)(bm + row) * K + kbase + sg * 8;
  }
  #pragma unroll
  for (int p = 0; p < BCH; ++p) {
    int row = (wave * BCH + p) * 8 + srow;
    bg[p] = B + (size_t)(bn + row) * K + kbase + sg * 8;
  }
  auto stage = [&](int buf) {
    #pragma unroll
    for (int p = 0; p < 4; ++p) { gload16(ag[p], &lA[buf][(wave * 4 + p) * 512]); ag[p] += 64; }
    #pragma unroll
    for (int p = 0; p < BCH; ++p) { gload16(bg[p], &lB[buf][(wave * BCH + p) * 512]); bg[p] += 64; }
  };
  f32x4 acc[4][NI] = {};
  int nt = klen / 64;
  stage(0);
  __syncthreads();
  int cur = 0;
  int lrow = lane & 15, glq = lane >> 4;
  for (int t = 0; t < nt; ++t) {
    if (t + 1 < nt) stage(cur ^ 1);
    short8 bf[2][NI];
    #pragma unroll
    for (int kk = 0; kk < 2; ++kk)
      #pragma unroll
      for (int ni = 0; ni < NI; ++ni) {
        int row = wn * (BN / 2) + ni * 16 + lrow;
        int pg = (kk * 4 + glq) ^ (row & 7);
        bf[kk][ni] = *(const short8*)&lB[cur][row * 64 + pg * 8];
      }
    #pragma unroll
    for (int mi = 0; mi < 4; ++mi)
      #pragma unroll
      for (int kk = 0; kk < 2; ++kk) {
        int row = wm * 64 + mi * 16 + lrow;
        int pg = (kk * 4 + glq) ^ (row & 7);
        short8 af = *(const short8*)&lA[cur][row * 64 + pg * 8];
        #pragma unroll
        for (int ni = 0; ni < NI; ++ni)
          acc[mi][ni] = __builtin_amdgcn_mfma_f32_16x16x32_bf16(af, bf[kk][ni], acc[mi][ni], 0, 0, 0);
      }
    __syncthreads();
    cur ^= 1;
  }
  #pragma unroll
  for (int mi = 0; mi < 4; ++mi)
    #pragma unroll
    for (int ni = 0; ni < NI; ++ni) {
      int col = bn + wn * (BN / 2) + ni * 16 + lrow;
      float bv = 0.f;
      if (BIAS) bv = (col < 512) ? bias0[col] : bias1[col - 512];
      #pragma unroll
      for (int j = 0; j < 4; ++j) {
        int row = bm + wm * 64 + mi * 16 + glq * 4 + j;
        float vv = acc[mi][ni][j] + bv;
        if (CBF16) {
          unsigned short* C = (unsigned short*)Cv + (size_t)blockIdx.z * M * N;
          C[(size_t)row * N + col] = f2bf(vv);
        } else {
          float* C = (float*)Cv + (size_t)blockIdx.z * M * N;
          C[(size_t)row * N + col] = vv;
        }
      }
    }
}

// ---------------- per-pair exp(score): 32-lane half per pair (2 pairs/wave) ----------------
// R14 form had 2 outstanding 16B loads/lane (latency-bound). Half-wave per pair:
// each lane loads 2 Q-chunks + 2 K-chunks = 4 outstanding; 2 pairs per wave.
// Chunk a = heads 0-3, chunk b = heads 4-7; 8-lane shfl reduce per head group.
__global__ __launch_bounds__(256) void k_scores(const unsigned short* __restrict__ QKb,
                                                const int* __restrict__ pairs,
                                                const unsigned char* __restrict__ vbits,
                                                float* __restrict__ es,
                                                float* __restrict__ sumexp,
                                                int* __restrict__ scnt) {
  int wave = threadIdx.x >> 6, lane = threadIdx.x & 63;
  int half = lane >> 5, hl = lane & 31;
  int e = (blockIdx.x * 4 + wave) * 2 + half;
  int2 pr = *(const int2*)&pairs[2 * e];
  int sub = pr.x, obj = pr.y;
  unsigned char nb = vbits[(size_t)sub * (N_INST / 4) + (obj >> 2)];
  bool valid = (sub != obj) && ((nb >> (obj & 3)) & 1);
  if (!valid && hl == 0) es[(size_t)e * 8] = -1.f;
  if (__ballot(valid) == 0ull) return;   // both halves invalid -> retire wave
  float pa = 0.f, pb = 0.f;
  if (valid) {
    short8 qa = *(const short8*)&QKb[(size_t)sub * 1024 + hl * 8];
    short8 qb = *(const short8*)&QKb[(size_t)sub * 1024 + 256 + hl * 8];
    short8 ka = *(const short8*)&QKb[(size_t)obj * 1024 + 512 + hl * 8];
    short8 kb = *(const short8*)&QKb[(size_t)obj * 1024 + 768 + hl * 8];
    #pragma unroll
    for (int j = 0; j < 8; ++j) {
      pa += bf2f((unsigned short)qa[j]) * bf2f((unsigned short)ka[j]);
      pb += bf2f((unsigned short)qb[j]) * bf2f((unsigned short)kb[j]);
    }
  }
  pa += __shfl_xor(pa, 1); pa += __shfl_xor(pa, 2); pa += __shfl_xor(pa, 4);
  pb += __shfl_xor(pb, 1); pb += __shfl_xor(pb, 2); pb += __shfl_xor(pb, 4);
  if (valid && (hl & 7) == 0) {
    int g = hl >> 3;                     // head group 0..3
    float ea = expf(pa * 0.125f);        // heads 0-3
    float eb = expf(pb * 0.125f);        // heads 4-7
    es[(size_t)e * 8 + g] = ea;
    es[(size_t)e * 8 + 4 + g] = eb;
    atomicAdd(&sumexp[sub * 8 + g], ea);
    atomicAdd(&sumexp[sub * 8 + 4 + g], eb);
    if (g == 0) atomicAdd(&scnt[sub], 1);
  }
}

// ---------------- per-row denominators -> invden, base ----------------
__global__ __launch_bounds__(256) void k_denom(const float* __restrict__ sumexp,
                                               const int* __restrict__ scnt,
                                               const int* __restrict__ acnt,
                                               float* __restrict__ invden,
                                               float* __restrict__ base) {
  int i = blockIdx.x * 256 + threadIdx.x;
  if (i >= N_INST) return;
  float c0 = (float)(acnt[i] - scnt[i]);
  const float E0 = expf(1e-7f);
  float bsum = 0.f;
  #pragma unroll
  for (int h = 0; h < NHEAD; ++h) {
    float inv = 1.0f / (E0 + c0 + sumexp[i * NHEAD + h]);
    invden[i * NHEAD + h] = inv;
    bsum += inv;
  }
  base[i] = bsum * (1.0f / NHEAD);
}

// ---------------- scatter ratio entries into mask ----------------
__global__ __launch_bounds__(256) void k_scatter(const int* __restrict__ pairs,
                                                 const float* __restrict__ es,
                                                 const float* __restrict__ invden,
                                                 const float* __restrict__ base,
                                                 unsigned short* __restrict__ maskb) {
  int e = blockIdx.x * 256 + threadIdx.x;
  if (e >= NPAIR) return;
  float4 e0 = *(const float4*)&es[(size_t)e * 8];
  if (e0.x < 0.f) return;
  float4 e1 = *(const float4*)&es[(size_t)e * 8 + 4];
  int sub = pairs[2 * e], obj = pairs[2 * e + 1];
  const float* inv = &invden[sub * 8];
  float f = e0.x * inv[0] + e0.y * inv[1] + e0.z * inv[2] + e0.w * inv[3] +
            e1.x * inv[4] + e1.y * inv[5] + e1.z * inv[6] + e1.w * inv[7];
  maskb[(size_t)sub * N_INST + obj] = f2bf(f * 0.125f / base[sub]);
}

// ---------------- reduce split-K=4 bf16 partials + row scale ----------------
__global__ __launch_bounds__(256) void k_redscale(const unsigned short* __restrict__ P,
                                                  const float* __restrict__ base,
                                                  float* __restrict__ out) {
  size_t idx = ((size_t)blockIdx.x * 256 + threadIdx.x) * 4;
  int i = (int)(idx >> 9);
  const size_t S = (size_t)N_INST * 512;
  u16x4 a = *(const u16x4*)&P[idx];
  u16x4 b = *(const u16x4*)&P[idx + S];
  u16x4 c = *(const u16x4*)&P[idx + 2 * S];
  u16x4 d = *(const u16x4*)&P[idx + 3 * S];
  float s = base[i];
  float4 o;
  o.x = s * (bf2f(a[0]) + bf2f(b[0]) + bf2f(c[0]) + bf2f(d[0]));
  o.y = s * (bf2f(a[1]) + bf2f(b[1]) + bf2f(c[1]) + bf2f(d[1]));
  o.z = s * (bf2f(a[2]) + bf2f(b[2]) + bf2f(c[2]) + bf2f(d[2]));
  o.w = s * (bf2f(a[3]) + bf2f(b[3]) + bf2f(c[3]) + bf2f(d[3]));
  *(float4*)&out[idx] = o;
}

extern "C" void kernel_launch(void* const* d_in, const int* in_sizes, int n_in,
                              void* d_out, int out_size, void* d_ws, size_t ws_size,
                              hipStream_t stream) {
  const float* x   = (const float*)d_in[0];
  const float* agg = (const float*)d_in[1];
  const int*   prs = (const int*)d_in[2];
  const float* w_q = (const float*)d_in[3];
  const float* b_q = (const float*)d_in[4];
  const float* w_k = (const float*)d_in[5];
  const float* b_k = (const float*)d_in[6];
  float* out = (float*)d_out;

  char* ws = (char*)d_ws;
  size_t off = 0;
  auto alloc = [&](size_t bytes) -> void* {
    void* p = ws + off;
    off += (bytes + 255) & ~(size_t)255;
    return p;
  };
  unsigned short* xb    = (unsigned short*)alloc((size_t)N_INST * D_FEAT * 2);
  unsigned short* xbT   = (unsigned short*)alloc((size_t)D_FEAT * N_INST * 2);
  unsigned short* wqkb  = (unsigned short*)alloc((size_t)1024 * D_FEAT * 2);
  void*           QKP   = alloc((size_t)N_INST * 512 * 2 * 4);  // 8MB QK bf16 table; reused as 4x bf16 partials (16MB)
  float*          es    = (float*)alloc((size_t)NPAIR * NHEAD * 4);
  float*          sumexp= (float*)alloc((size_t)N_INST * NHEAD * 4);
  int*            scnt  = (int*)alloc((size_t)N_INST * 4);
  int*            acnt  = (int*)alloc((size_t)N_INST * 4);
  float*          invden= (float*)alloc((size_t)N_INST * NHEAD * 4);
  float*          base  = (float*)alloc((size_t)N_INST * 4);
  unsigned char*  vbits = (unsigned char*)alloc((size_t)N_INST * (N_INST / 4));
  unsigned short* maskb = (unsigned short*)alloc((size_t)N_INST * N_INST * 2);

  hipMemsetAsync(sumexp, 0, (size_t)N_INST * NHEAD * 4, stream);
  hipMemsetAsync(scnt, 0, (size_t)N_INST * 4, stream);

  k_castw<<<dim3(D_FEAT * D_FEAT / 4 / 256, 2), 256, 0, stream>>>(w_q, w_k, wqkb);
  k_xprep<<<dim3(D_FEAT / 32, N_INST / 32), 256, 0, stream>>>(x, xb, xbT);
  k_mask_acnt<<<dim3(N_INST / 2), 256, 0, stream>>>(agg, maskb, acnt, vbits);

  // fused Q|K projection: C (4096x1024 bf16) = xb (4096x512) * wqkb (1024x512)^T + bias
  k_gemm<1, 1, 64><<<dim3(1024 / 64, N_INST / 128, 1), 256, 0, stream>>>(
      xb, wqkb, b_q, b_k, QKP, N_INST, 1024, D_FEAT, D_FEAT);

  k_scores<<<dim3(NPAIR / 8), 256, 0, stream>>>((const unsigned short*)QKP, prs, vbits, es, sumexp, scnt);
  k_denom<<<dim3(N_INST / 256), 256, 0, stream>>>(sumexp, scnt, acnt, invden, base);
  k_scatter<<<dim3(NPAIR / 256), 256, 0, stream>>>(prs, es, invden, base, maskb);

  // bf16 partials = maskb (4096x4096) * xbT (512x4096)^T, 128x128 tile, split-K=4
  k_gemm<0, 1, 128><<<dim3(512 / 128, N_INST / 128, 4), 256, 0, stream>>>(
      maskb, xbT, nullptr, nullptr, QKP, N_INST, 512, N_INST, N_INST / 4);

  k_redscale<<<dim3(N_INST * 512 / 4 / 256), 256, 0, stream>>>((const unsigned short*)QKP, base, out);
}